// Round 14
// baseline (170.872 us; speedup 1.0000x reference)
//
#include <hip/hip_runtime.h>

#define Bn 8
#define Ln 128
#define Hn 768
#define Pn 16
#define Dn 102
#define EPSF 1e-8f
#define NINF -1e30f

typedef __attribute__((ext_vector_type(8))) short bfrag8;
typedef __attribute__((ext_vector_type(4))) float f32x4;
union FragU { unsigned u[4]; bfrag8 v; };

#define MFMA16(A,B,C) __builtin_amdgcn_mfma_f32_16x16x32_bf16((A),(B),(C),0,0,0)

__device__ __forceinline__ float wred_sum(float v){
#pragma unroll
  for(int o=32;o>=1;o>>=1) v += __shfl_xor(v,o);
  return v;
}
__device__ __forceinline__ float wred_max(float v){
#pragma unroll
  for(int o=32;o>=1;o>>=1) v = fmaxf(v,__shfl_xor(v,o));
  return v;
}
__device__ __forceinline__ float qred_sum(float v){
  v += __shfl_xor(v,16);
  v += __shfl_xor(v,32);
  return v;
}

// truncation split: x = hi + lo + O(2^-16 x); packs 8 f32 -> bf16x8 hi/lo frags
__device__ __forceinline__ void split8(const float* x, FragU& H, FragU& L){
  float r[8];
#pragma unroll
  for(int q=0;q<8;q++){
    unsigned hb = __float_as_uint(x[q]) & 0xffff0000u;
    r[q] = x[q] - __uint_as_float(hb);
  }
#pragma unroll
  for(int q=0;q<4;q++){
    H.u[q] = __builtin_amdgcn_perm(__float_as_uint(x[2*q+1]), __float_as_uint(x[2*q]), 0x07060302u);
    L.u[q] = __builtin_amdgcn_perm(__float_as_uint(r[2*q+1]), __float_as_uint(r[2*q]), 0x07060302u);
  }
}

// async global->LDS DMA: per-lane global src; LDS dest = wave-uniform base + lane*16
#define GLD_LDS(gp, lp) __builtin_amdgcn_global_load_lds( \
    (const __attribute__((address_space(1))) void*)(gp), \
    (__attribute__((address_space(3))) void*)(lp), 16, 0, 0)

// ---- workspace layout (float element offsets) ----
constexpr size_t SZ_MAT   = (size_t)Bn*Ln*Hn;              // 786432
constexpr size_t OFF_C1F  = 0;
constexpr size_t OFF_C2F  = OFF_C1F + SZ_MAT;
constexpr size_t OFF_COS  = OFF_C2F + SZ_MAT;              // B*L*L
constexpr size_t OFF_N1   = OFF_COS + (size_t)Bn*Ln*Ln;    // B*L
constexpr size_t OFF_N2   = OFF_N1 + (size_t)Bn*Ln;
constexpr size_t OFF_WN   = OFF_N2 + (size_t)Bn*Ln;        // 2*5*B*P*L
constexpr size_t OFF_W2T  = OFF_WN + (size_t)2*5*Bn*Pn*Ln; // 5*H*P [X][h][p]
constexpr size_t OFF_MVMAX  = OFF_W2T + (size_t)5*Hn*Pn;   // 2*B*L*P
constexpr size_t OFF_MVMEAN = OFF_MVMAX + (size_t)2*Bn*Ln*Pn;
constexpr size_t OFF_PART   = OFF_MVMEAN + (size_t)2*Bn*Ln*Pn; // B*L*P*32*2 (side1)
constexpr size_t OFF_LENS   = OFF_PART + (size_t)Bn*Ln*Pn*32*2; // 32 ints
constexpr size_t OFF_C2H    = OFF_LENS + 32;               // B*12*128*64 ushort = 393216 floats
constexpr size_t OFF_C2L    = OFF_C2H + (size_t)Bn*12*128*64/2;
constexpr size_t OFF_W2F    = OFF_C2L + (size_t)Bn*12*128*64/2; // 24*2*64*4 = 12288 floats
constexpr size_t OFF_W2B    = OFF_W2F + 12288;             // 5*48*64*4 = 61440 floats

__device__ __forceinline__ size_t wnIdx(int side,int X,int b,int p,int i){
  return ((((size_t)side*5 + X)*Bn + b)*Pn + p)*Ln + i;
}

// ---------------- k_prep: lengths + weight tables (W2T [X][h][p], W2F frag-linear mp, W2B frag-linear all-X) ----------------
__global__ __launch_bounds__(256) void k_prep(
    const float* __restrict__ m1, const float* __restrict__ m2,
    const float* __restrict__ wff, const float* __restrict__ wfb,
    const float* __restrict__ wmp, const float* __restrict__ watt,
    const float* __restrict__ wmatt,
    float* __restrict__ W2T, float* __restrict__ W2F, float* __restrict__ W2B,
    int* __restrict__ lens){
  int t = threadIdx.x;
  const float* srcs[5] = {wff,wfb,wmp,watt,wmatt};
  if(blockIdx.x < 8){
    int b = blockIdx.x;
    __shared__ int cnt[2];
    if(t<2) cnt[t]=0;
    __syncthreads();
    if(t<Ln){
      if(m1[b*Ln+t]>0.5f) atomicAdd(&cnt[0],1);
      if(m2[b*Ln+t]>0.5f) atomicAdd(&cnt[1],1);
    }
    __syncthreads();
    if(t==0){
      lens[b]=cnt[0]; lens[8+b]=cnt[1];
      lens[16+b]=max(cnt[0]-1,0); lens[24+b]=max(cnt[1]-1,0);
    }
  } else if(blockIdx.x < 248){
    int idx = (blockIdx.x-8)*256 + t;     // < 5*768*16 = 61440
    int X = idx/(Pn*Hn);
    int r = idx%(Pn*Hn);
    int h = r/Pn, p = r%Pn;
    float w = srcs[X][p*Hn+h];
    W2T[idx] = w*w;                        // layout [X][h][p]
  } else if(blockIdx.x < 296){
    // W2F: fragment-linear fp32 w2 for mp: [ksg 24][half 2][64 lanes][4]
    int idx = (blockIdx.x-248)*256 + t;    // < 12288
    int ksg = idx>>9;
    int r   = idx&511;
    int half= r>>8;
    int li  = (r>>2)&63;
    int e4  = r&3;
    int h = ksg*32 + half*16 + ((li>>4)<<2) + e4;
    int p = li&15;
    float w = wmp[p*Hn+h];
    W2F[idx] = w*w;
  } else {
    // W2B: k_fin Phase-B frag-linear: [X 5][hh4 48][lane 64][4]
    // entry = w2[p = lane&15][h = (lane>>4)*192 + hh4*4 + e]
    int idx = (blockIdx.x-296)*256 + t;    // < 61440
    int X   = idx/12288;
    int r   = idx%12288;
    int hh4 = r>>8;
    int li  = (r>>2)&63;
    int e   = r&3;
    int h = (li>>4)*192 + hh4*4 + e;
    int p = li&15;
    float w = srcs[X][p*Hn+h];
    W2B[idx] = w*w;
  }
}

// ---------------- k_rows: 4 rows/block; masked rows + norms + bf16 split + p-in-thread weighted norms ----------------
// grid (Ln/4, Bn, 2), 256 thr.
__global__ __launch_bounds__(256) void k_rows(
    const float* __restrict__ ctx1, const float* __restrict__ m1,
    const float* __restrict__ ctx2, const float* __restrict__ m2,
    const float* __restrict__ W2T,
    float* __restrict__ c1f, float* __restrict__ c2f,
    unsigned short* __restrict__ c2h, unsigned short* __restrict__ c2l,
    float* __restrict__ n1, float* __restrict__ n2, float* __restrict__ wn){
  const int i0 = blockIdx.x*4, b = blockIdx.y, side = blockIdx.z;
  const float* ctx = side? ctx2 : ctx1;
  const float* msk = side? m2 : m1;
  float* dst = side? c2f : c1f;
  float* nD  = side? n2 : n1;
  const int t = threadIdx.x, w = t>>6, l = t&63;

  __shared__ float red4[4][4];
  __shared__ float redX[4][4][16];   // [wave][pq][r*4+pi]
  __shared__ float mkS[4];

  if(t<4) mkS[t] = msk[b*Ln+i0+t];

  // ---- Phase 1: masked write-out + bf16 split + norms (4 rows) ----
#pragma unroll
  for(int r=0;r<4;r++){
    const int i = i0+r;
    const float mk = msk[b*Ln+i];
    const size_t base = ((size_t)(b*Ln+i))*Hn;
    float ss = 0.f;
#pragma unroll
    for(int k=0;k<3;k++){
      float x = ctx[base + t + 256*k]*mk;
      dst[base + t + 256*k] = x;
      ss = fmaf(x,x,ss);
      if(side==1){
        int h = t+256*k;
        int kc = h>>6, hw = h&63, u = hw>>2, e = hw&3;
        int pos = ((u ^ (i&15))<<2) + e;
        size_t o = ((size_t)(b*12+kc)*128 + i)*64 + pos;
        unsigned hb = __float_as_uint(x) & 0xffff0000u;
        float rem = x - __uint_as_float(hb);
        c2h[o] = (unsigned short)(hb>>16);
        c2l[o] = (unsigned short)(__float_as_uint(rem)>>16);
      }
    }
    ss = wred_sum(ss);
    if(l==0) red4[r][w]=ss;
  }
  __syncthreads();
  if(t<4) nD[b*Ln+i0+t] = sqrtf(fmaxf(red4[t][0]+red4[t][1]+red4[t][2]+red4[t][3],0.f));

  // ---- Phase 2: weighted norms, thread = (hc: h-block of 12, pq: 4 p's) ----
  const int pq = t&3, hc = t>>2;
  const int h0 = hc*12;
  float v2r[4][12];
#pragma unroll
  for(int r=0;r<4;r++){
    const float mk = mkS[r];
    const float* src = ctx + ((size_t)(b*Ln+i0+r))*Hn + h0;
#pragma unroll
    for(int q=0;q<3;q++){
      float4 xv = *(const float4*)(src + q*4);
      v2r[r][q*4+0]=xv.x*xv.x*mk; v2r[r][q*4+1]=xv.y*xv.y*mk;
      v2r[r][q*4+2]=xv.z*xv.z*mk; v2r[r][q*4+3]=xv.w*xv.w*mk;
    }
  }
  for(int X=0;X<5;++X){
    float acc[4][4];
#pragma unroll
    for(int r=0;r<4;r++){ acc[r][0]=0.f; acc[r][1]=0.f; acc[r][2]=0.f; acc[r][3]=0.f; }
    const float* wb = W2T + (size_t)X*Hn*Pn + pq*4;
#pragma unroll
    for(int h=0;h<12;h++){
      float4 w4 = *(const float4*)(wb + (size_t)(h0+h)*Pn);
#pragma unroll
      for(int r=0;r<4;r++){
        acc[r][0]=fmaf(w4.x,v2r[r][h],acc[r][0]);
        acc[r][1]=fmaf(w4.y,v2r[r][h],acc[r][1]);
        acc[r][2]=fmaf(w4.z,v2r[r][h],acc[r][2]);
        acc[r][3]=fmaf(w4.w,v2r[r][h],acc[r][3]);
      }
    }
#pragma unroll
    for(int r=0;r<4;r++)
#pragma unroll
      for(int pi=0;pi<4;pi++){
        float v = acc[r][pi];
        v += __shfl_xor(v,4); v += __shfl_xor(v,8);
        v += __shfl_xor(v,16); v += __shfl_xor(v,32);
        acc[r][pi]=v;
      }
    if(l<4){
#pragma unroll
      for(int r=0;r<4;r++)
#pragma unroll
        for(int pi=0;pi<4;pi++) redX[w][l][r*4+pi]=acc[r][pi];
    }
    __syncthreads();
    if(t<64){
      int r = t>>4, p = t&15;
      int pqi = p>>2, pii = p&3;
      float s = redX[0][pqi][r*4+pii]+redX[1][pqi][r*4+pii]
               +redX[2][pqi][r*4+pii]+redX[3][pqi][r*4+pii];
      wn[wnIdx(side,X,b,p,i0+r)] = s;
    }
    __syncthreads();
  }
}

// ---------------- k_mm: MFMA split-bf16 e-tensor + cos ----------------
// grid (Bn, 32): block = (b, 4 i, all 128 j). 512 thr = 8 waves (jtp:4, ihalf:2).
__global__ __launch_bounds__(512) void k_mm(
    const float* __restrict__ c1f,
    const unsigned short* __restrict__ c2h, const unsigned short* __restrict__ c2l,
    const float* __restrict__ W2F, const float* __restrict__ WN,
    const float* __restrict__ n1, const float* __restrict__ n2,
    const float* __restrict__ m1, const float* __restrict__ m2,
    const int* __restrict__ lens,
    float* __restrict__ cosM,
    float* __restrict__ mvmax, float* __restrict__ mvmean,
    float* __restrict__ part){
  const int b = blockIdx.x, ig = blockIdx.y, ibase = ig*4;
  const int t = threadIdx.x, l = t&63;
  const int wid = __builtin_amdgcn_readfirstlane(t>>6);
  const int jtp = wid&3, ihalf = wid>>2;
  const int p = l&15, g4 = l>>4;

  __shared__ __align__(16) unsigned short sB2h[2][128][64];  // 32 KB
  __shared__ __align__(16) unsigned short sB2l[2][128][64];  // 32 KB
  __shared__ __align__(16) float sw2[2][1024];               // 8 KB [ks][half][64][4]
  __shared__ __align__(16) float sa[2][4][64];               // 2 KB (swizzled units)
  __shared__ float sm2s[Ln];
  __shared__ float red0[2][4][2][16][2];                     // [ihalf][jtp][ii][p][M,S]

  const size_t c2elem = (size_t)b*12*8192;   // ushort elements to chunk 0 of b

  // ---- prologue: DMA chunk 0 (B2 hi/lo, w2f), stage sm2 + a(kc0) ----
  {
#pragma unroll
    for(int k=0;k<2;k++){
      GLD_LDS((const char*)c2h + c2elem*2 + (2*wid+k)*1024 + l*16,
              (char*)&sB2h[0][0][0] + (2*wid+k)*1024);
      GLD_LDS((const char*)c2l + c2elem*2 + (2*wid+k)*1024 + l*16,
              (char*)&sB2l[0][0][0] + (2*wid+k)*1024);
    }
    if(wid>=4){
      int q = wid-4;
      GLD_LDS((const char*)W2F + q*1024 + l*16,
              (char*)&sw2[0][0] + q*1024);
    }
    if(t<Ln) sm2s[t] = m2[b*Ln+t];
    if(t<64){
      int row = t>>4, u = t&15;
      float4 av = *(const float4*)(c1f + ((size_t)(b*Ln+ibase+row))*Hn + u*4);
      *(float4*)&sa[0][row][(u ^ (row&3))<<2] = av;
    }
  }
  __syncthreads();

  f32x4 accE[2][2]; f32x4 accC[2];
#pragma unroll
  for(int q=0;q<2;q++){
    accC[q] = (f32x4){0.f,0.f,0.f,0.f};
#pragma unroll
    for(int ii=0;ii<2;ii++) accE[q][ii] = (f32x4){0.f,0.f,0.f,0.f};
  }

  for(int c=0; c<12; ++c){
    const int cur = c&1, nxt = cur^1;
    const bool more = (c+1<12);
    float4 aN;
    if(more){
      const size_t cb2 = (c2elem + (size_t)(c+1)*8192)*2;   // bytes
#pragma unroll
      for(int k=0;k<2;k++){
        GLD_LDS((const char*)c2h + cb2 + (2*wid+k)*1024 + l*16,
                (char*)&sB2h[nxt][0][0] + (2*wid+k)*1024);
        GLD_LDS((const char*)c2l + cb2 + (2*wid+k)*1024 + l*16,
                (char*)&sB2l[nxt][0][0] + (2*wid+k)*1024);
      }
      if(wid>=4){
        int q = wid-4;
        GLD_LDS((const char*)W2F + (c+1)*4096 + q*1024 + l*16,
                (char*)&sw2[nxt][0] + q*1024);
      }
      if(t<64){
        int row = t>>4, u = t&15;
        aN = *(const float4*)(c1f + ((size_t)(b*Ln+ibase+row))*Hn + (c+1)*64 + u*4);
      }
    }
#pragma unroll
    for(int ks=0; ks<2; ++ks){
      f32x4 w20 = *(const f32x4*)&sw2[cur][(ks*2+0)*256 + (l<<2)];
      f32x4 w21 = *(const f32x4*)&sw2[cur][(ks*2+1)*256 + (l<<2)];
      FragU Bh[2], Bl[2];
#pragma unroll
      for(int q=0;q<2;q++){
        int jt = jtp + 4*q;
        int j  = jt*16 + p;
        const char* bh = (const char*)&sB2h[cur][0][0] + j*128;
        const char* bl = (const char*)&sB2l[cur][0][0] + j*128;
        int u1 = (ks*8 + g4)     ^ (j&15);
        int u2 = (ks*8 + 4 + g4) ^ (j&15);
        uint2 h0 = *(const uint2*)(bh + (u1<<3));
        uint2 h1 = *(const uint2*)(bh + (u2<<3));
        uint2 l0 = *(const uint2*)(bl + (u1<<3));
        uint2 l1 = *(const uint2*)(bl + (u2<<3));
        Bh[q].u[0]=h0.x; Bh[q].u[1]=h0.y; Bh[q].u[2]=h1.x; Bh[q].u[3]=h1.y;
        Bl[q].u[0]=l0.x; Bl[q].u[1]=l0.y; Bl[q].u[2]=l1.x; Bl[q].u[3]=l1.y;
      }
      if(ihalf==0){
        int ar = p&3;
        const float* sar = &sa[cur][ar][0];
        f32x4 a0 = *(const f32x4*)(sar + (((ks*8+g4)  ^ar)<<2));
        f32x4 a1 = *(const f32x4*)(sar + (((ks*8+4+g4)^ar)<<2));
        float xv[8] = {a0[0],a0[1],a0[2],a0[3], a1[0],a1[1],a1[2],a1[3]};
        FragU Ah, Al; split8(xv, Ah, Al);
#pragma unroll
        for(int q=0;q<2;q++){
          accC[q] = MFMA16(Bh[q].v, Ah.v, accC[q]);
          accC[q] = MFMA16(Bh[q].v, Al.v, accC[q]);
          accC[q] = MFMA16(Bl[q].v, Ah.v, accC[q]);
        }
      }
#pragma unroll
      for(int ii=0;ii<2;ii++){
        int row = ihalf*2+ii;
        const float* sar = &sa[cur][row][0];
        f32x4 a0 = *(const f32x4*)(sar + (((ks*8+g4)  ^(row&3))<<2));
        f32x4 a1 = *(const f32x4*)(sar + (((ks*8+4+g4)^(row&3))<<2));
        float xv[8] = {a0[0]*w20[0], a0[1]*w20[1], a0[2]*w20[2], a0[3]*w20[3],
                       a1[0]*w21[0], a1[1]*w21[1], a1[2]*w21[2], a1[3]*w21[3]};
        FragU Ah, Al; split8(xv, Ah, Al);
#pragma unroll
        for(int q=0;q<2;q++){
          accE[q][ii] = MFMA16(Bh[q].v, Ah.v, accE[q][ii]);
          accE[q][ii] = MFMA16(Bh[q].v, Al.v, accE[q][ii]);
          accE[q][ii] = MFMA16(Bl[q].v, Ah.v, accE[q][ii]);
        }
      }
    }
    if(more && t<64){
      int row = t>>4, u = t&15;
      *(float4*)&sa[nxt][row][(u ^ (row&3))<<2] = aN;
    }
    __syncthreads();   // one barrier/chunk: readers done + next DMA drained
  }

  // ---- epilogue: normalize, side0 (final), side1 (partial->part), cos ----
  const int len2 = min(max(lens[8+b],1),Ln);
  float sq1[2][4];
#pragma unroll
  for(int q=0;q<2;q++){
    int jt = jtp+4*q;
#pragma unroll
    for(int r=0;r<4;r++){
      int j = jt*16 + g4*4 + r;
      sq1[q][r] = sqrtf(fmaxf(WN[wnIdx(1,2,b,p,j)],0.f));
    }
  }
  float s1M[2][4], s1S[2][4];
#pragma unroll
  for(int q=0;q<2;q++)
#pragma unroll
    for(int r=0;r<4;r++){ s1M[q][r]=NINF; s1S[q][r]=0.f; }

#pragma unroll
  for(int ii=0;ii<2;ii++){
    int iR = ibase + ihalf*2 + ii;
    float sr = sqrtf(fmaxf(WN[wnIdx(0,2,b,p,iR)],0.f));
    float mr = m1[b*Ln+iR];
    float vmax=NINF, vsum=0.f;
#pragma unroll
    for(int q=0;q<2;q++){
      int jt = jtp+4*q;
#pragma unroll
      for(int r=0;r<4;r++){
        int j = jt*16 + g4*4 + r;
        float ev = accE[q][ii][r] / fmaxf(sr*sq1[q][r], EPSF);
        if(sm2s[j]!=0.f){ vmax=fmaxf(vmax,ev); vsum+=ev; }
        if(mr!=0.f){ s1M[q][r]=fmaxf(s1M[q][r],ev); s1S[q][r]+=ev; }
      }
    }
    vmax = fmaxf(vmax, __shfl_xor(vmax,16)); vmax = fmaxf(vmax, __shfl_xor(vmax,32));
    vsum += __shfl_xor(vsum,16); vsum += __shfl_xor(vsum,32);
    if(l<16){ red0[ihalf][jtp][ii][l][0]=vmax; red0[ihalf][jtp][ii][l][1]=vsum; }
  }
  float* red1 = (float*)&sB2h[0][0][0];   // alias (sB2 dead), 16 KB
  if(ihalf==1){
#pragma unroll
    for(int q=0;q<2;q++)
#pragma unroll
      for(int r=0;r<4;r++){
        int idx = (((jtp*2+q)*64 + l)*4 + r)*2;
        red1[idx]   = s1M[q][r];
        red1[idx+1] = s1S[q][r];
      }
  }
  __syncthreads();
  if(t<64){
    int ih_=t>>5, ii_=(t>>4)&1, p_=t&15;
    float M=NINF,S=0.f;
#pragma unroll
    for(int jq=0;jq<4;jq++){ M=fmaxf(M,red0[ih_][jq][ii_][p_][0]); S+=red0[ih_][jq][ii_][p_][1]; }
    int iR = ibase + ih_*2 + ii_;
    size_t o = ((size_t)(b*Ln+iR))*Pn + p_;
    mvmax[o]=M; mvmean[o]=S/(float)len2;   // side0: final (all j in block)
  }
  if(ihalf==0){
#pragma unroll
    for(int q=0;q<2;q++){
      int jt = jtp+4*q;
#pragma unroll
      for(int r=0;r<4;r++){
        int j = jt*16 + g4*4 + r;
        int idx = (((jtp*2+q)*64 + l)*4 + r)*2;
        float M = fmaxf(s1M[q][r], red1[idx]);
        float S = s1S[q][r] + red1[idx+1];
        size_t o = ((((size_t)(b*Ln+j))*Pn + p)*32 + ig)*2;
        part[o]=M; part[o+1]=S;
        float nj = fmaxf(n2[b*Ln+j], EPSF);
        if(p<4){
          int iR = ibase + p;
          float ni = fmaxf(n1[b*Ln+iR], EPSF);
          cosM[((size_t)(b*Ln+iR))*Ln + j] = accC[q][r]/(ni*nj);
        }
      }
    }
  }
}

// ---------------- k_mm2: combine side1 partials over 32 i-tiles ----------------
__global__ __launch_bounds__(256) void k_mm2(
    const float* __restrict__ part, const int* __restrict__ lens,
    float* __restrict__ mvmax, float* __restrict__ mvmean){
  int g = blockIdx.x*256 + threadIdx.x;   // 16384 = B*L*P
  int b = g>>11;
  const float4* q = (const float4*)(part + (size_t)g*64);
  float mx = NINF, sm = 0.f;
#pragma unroll
  for(int k=0;k<16;k++){
    float4 v = q[k];
    mx = fmaxf(mx, fmaxf(v.x, v.z));
    sm += v.y + v.w;
  }
  int len1 = min(max(lens[b],1),Ln);
  size_t o = (size_t)Bn*Ln*Pn + g;        // side 1 block of mv arrays
  mvmax[o] = mx;
  mvmean[o] = sm/(float)len1;
}

// ---------------- k_fin: attention + all 102 features; 4 rows/block, 8 waves ----------------
// grid (16, Ln/4), 512 thr: x = side*8+b → XCD = b
// R12/R13 lesson: k_fin pinned at 44-47µs in both 2-row (high occ, 2x panel reads)
// and 4-row (best reuse, grid-capped 8 waves/CU) forms. Fix: 4-row geometry with
// 512 threads = 8 waves — attention j-loop SPLIT across wave-halves (partials
// merged via bank-coprime LDS scratch), Phase B rows split across wave-pairs.
// Per-wave serial work halves; waves/CU double to 16.
#define HPAD 784              // 768 + 4*4
__global__ __launch_bounds__(512) void k_fin(
    const float* __restrict__ c1f, const float* __restrict__ c2f,
    const float* __restrict__ cosM,
    const float* __restrict__ n1, const float* __restrict__ n2,
    const float* __restrict__ wn, const float* __restrict__ W2B,
    const float* __restrict__ mvmax, const float* __restrict__ mvmean,
    const int* __restrict__ lens,
    const float* __restrict__ m1, const float* __restrict__ m2,
    float* __restrict__ out){
  const int x = blockIdx.x, side = x>>3, b = x&7;
  const int r0 = blockIdx.y*4;
  const int t = threadIdx.x, w = t>>6, l = t&63;
  const int jh = t>>8, tt = t&255;       // j-half / h-owner
  const float* selfF  = side? c2f : c1f;
  const float* otherF = side? c1f : c2f;
  const float* nSelf  = side? n2 : n1;
  const float* nOther = side? n1 : n2;
  const float* mInner = side? m1 : m2;
  const float* mSelfm = side? m2 : m1;
  int lenI = side? lens[b]    : lens[8+b];
  int lpO  = side? lens[16+b] : lens[24+b];
  lenI = min(max(lenI,1),Ln);
  lpO  = min(max(lpO,0),Ln-1);

  __shared__ float cS[4*Ln];
  __shared__ float mS[Ln];
  __shared__ __align__(16) float sV1[4][HPAD];
  __shared__ __align__(16) float sF[HPAD], sB[HPAD];
  __shared__ __align__(16) float sAS[4][HPAD], sAM[4][HPAD];
  __shared__ float scr[256*25];          // merge scratch: stride 25 (bank-coprime)
  __shared__ float redm[4][4], reds[4][4];

  // ---- stage (512 threads; padded: float4-unit q -> q + q/48) ----
  {
    if(side==0){
      const float* crow = cosM + ((size_t)(b*Ln+r0))*Ln;
      for(int idx=t; idx<4*Ln; idx+=512) cS[idx]=crow[idx];
    } else {
      for(int idx=t; idx<4*Ln; idx+=512){
        int jj = idx&127, rp = idx>>7;   // transposed: cos^T[r][j] = cosM[j][r]
        cS[rp*Ln+jj] = cosM[((size_t)(b*Ln+jj))*Ln + r0+rp];
      }
    }
    if(t<Ln) mS[t]=mInner[b*Ln+t];
    const float4* s4 = (const float4*)(selfF + ((size_t)(b*Ln+r0))*Hn);
    for(int idx=t; idx<4*Hn/4; idx+=512){
      int row = idx/192, q = idx - row*192;
      ((float4*)&sV1[row][0])[q + q/48] = s4[idx];
    }
    const float4* f4 = (const float4*)(otherF + ((size_t)(b*Ln+lpO))*Hn);
    const float4* b4 = (const float4*)(otherF + ((size_t)(b*Ln))*Hn);
    if(t<Hn/4){
      ((float4*)sF)[t + t/48]=f4[t];
      ((float4*)sB)[t + t/48]=b4[t];
    }
  }
  __syncthreads();

  // ---- attention accumulation (4 rows, h = 3tt..3tt+2); j-range split by jh ----
  float aS[4][3], aM[4][3];
#pragma unroll
  for(int r=0;r<4;r++)
#pragma unroll
    for(int k=0;k<3;k++){ aS[r][k]=0.f; aM[r][k]=NINF; }
  {
    const int half = (lenI+1)>>1;
    const int jbeg = jh? half : 0;
    const int jend = jh? lenI : half;
    const float* src = otherF + (size_t)b*Ln*Hn;
#pragma unroll 2
    for(int jj=jbeg; jj<jend; ++jj){     // jj<lenI => mS[jj]!=0 (prefix mask)
      float3 vk = ((const float3*)(src + (size_t)jj*Hn))[tt];
      float c0=cS[jj], c1v=cS[Ln+jj], c2v=cS[2*Ln+jj], c3v=cS[3*Ln+jj];
      aS[0][0]=fmaf(vk.x,c0 ,aS[0][0]); aS[0][1]=fmaf(vk.y,c0 ,aS[0][1]); aS[0][2]=fmaf(vk.z,c0 ,aS[0][2]);
      aS[1][0]=fmaf(vk.x,c1v,aS[1][0]); aS[1][1]=fmaf(vk.y,c1v,aS[1][1]); aS[1][2]=fmaf(vk.z,c1v,aS[1][2]);
      aS[2][0]=fmaf(vk.x,c2v,aS[2][0]); aS[2][1]=fmaf(vk.y,c2v,aS[2][1]); aS[2][2]=fmaf(vk.z,c2v,aS[2][2]);
      aS[3][0]=fmaf(vk.x,c3v,aS[3][0]); aS[3][1]=fmaf(vk.y,c3v,aS[3][1]); aS[3][2]=fmaf(vk.z,c3v,aS[3][2]);
      aM[0][0]=fmaxf(aM[0][0],vk.x*c0 ); aM[0][1]=fmaxf(aM[0][1],vk.y*c0 ); aM[0][2]=fmaxf(aM[0][2],vk.z*c0 );
      aM[1][0]=fmaxf(aM[1][0],vk.x*c1v); aM[1][1]=fmaxf(aM[1][1],vk.y*c1v); aM[1][2]=fmaxf(aM[1][2],vk.z*c1v);
      aM[2][0]=fmaxf(aM[2][0],vk.x*c2v); aM[2][1]=fmaxf(aM[2][1],vk.y*c2v); aM[2][2]=fmaxf(aM[2][2],vk.z*c2v);
      aM[3][0]=fmaxf(aM[3][0],vk.x*c3v); aM[3][1]=fmaxf(aM[3][1],vk.y*c3v); aM[3][2]=fmaxf(aM[3][2],vk.z*c3v);
    }
  }
  // ---- merge jh halves via scratch (jh1 writes, jh0 combines) ----
  if(jh==1){
    float* sp = scr + tt*25;
#pragma unroll
    for(int r=0;r<4;r++)
#pragma unroll
      for(int k=0;k<3;k++){ sp[r*6+k*2]=aS[r][k]; sp[r*6+k*2+1]=aM[r][k]; }
  }
  __syncthreads();
  if(jh==0){
    const float* sp = scr + tt*25;
#pragma unroll
    for(int r=0;r<4;r++)
#pragma unroll
      for(int k=0;k<3;k++){
        aS[r][k] += sp[r*6+k*2];
        aM[r][k] = fmaxf(aM[r][k], sp[r*6+k*2+1]);
      }
  }

  // ---- softmax over h (4 rows); jh0 waves (0..3) only ----
  if(jh==0){
#pragma unroll
    for(int r=0;r<4;r++){
      float lm = fmaxf(fmaxf(aS[r][0],aS[r][1]),aS[r][2]);
      lm = wred_max(lm);
      if(l==0) redm[r][w]=lm;
    }
  }
  __syncthreads();
  if(jh==0){
    float bm[4];
#pragma unroll
    for(int r=0;r<4;r++)
      bm[r] = fmaxf(fmaxf(redm[r][0],redm[r][1]),fmaxf(redm[r][2],redm[r][3]));
    float ev[4][3];
#pragma unroll
    for(int r=0;r<4;r++){
      float es=0.f;
#pragma unroll
      for(int k=0;k<3;k++){ ev[r][k]=expf(aS[r][k]-bm[r]); es+=ev[r][k]; }
      es = wred_sum(es);
      if(l==0) reds[r][w]=es;
      aS[r][0]=ev[r][0]; aS[r][1]=ev[r][1]; aS[r][2]=ev[r][2];  // reuse regs
    }
  }
  __syncthreads();
  if(jh==0){
    const float u = 1.f/(float)Hn;
#pragma unroll
    for(int r=0;r<4;r++){
      float smr = mSelfm[b*Ln+r0+r];
      float bs = reds[r][0]+reds[r][1]+reds[r][2]+reds[r][3];
      float inv = 1.f/fmaxf(bs,EPSF);
#pragma unroll
      for(int k=0;k<3;k++){
        int h = 3*tt+k;
        int hi = h + ((h/192)<<2);
        sAS[r][hi] = (smr!=0.f)? aS[r][k]*inv : u;
        sAM[r][hi] = aM[r][k];
      }
    }
  }
  __syncthreads();

  // ---- Phase A (waves 0-3, row = w) + Phase C (waves 4-5, t in [256,384)) ----
  if(w<4){
    int rr = w;
    float cmx=NINF, csm=0.f;
    float ca = cS[rr*Ln + l], cb = cS[rr*Ln + l + 64];
    if(mS[l]!=0.f){ cmx=ca; csm=ca; }
    if(mS[l+64]!=0.f){ cmx=fmaxf(cmx,cb); csm+=cb; }
    cmx = wred_max(cmx); csm = wred_sum(csm);
    if(l==0){
      float* op = out + ((size_t)((b*2+side)*Ln + r0+rr))*Dn;
      op[0] = cmx;
      op[1] = csm/(float)lenI;
    }
  } else if(t>=256 && t<384){
    int q = t-256;
    int rr = q>>5, qq = q&31, p = qq&15;
    size_t o = ((size_t)((side*Bn+b)*Ln + r0+rr))*Pn + p;
    float* op = out + ((size_t)((b*2+side)*Ln + r0+rr))*Dn;
    if(qq<16) op[36+p] = mvmax[o];
    else      op[52+p] = mvmean[o];
  }

  // ---- Phase B: wave w handles X=Xids[w&3] for rows {2*(w>>2), +1} ----
  {
    const int Xids[4] = {0,1,3,4};
    const int offS[4] = {2,19,68,85};
    const int X = Xids[w&3], offs = offS[w&3];
    const bool dyn = ((w&3)>=2);
    const int rp = (w>>2)*2;               // row-pair base
    const int p = l&15, hq = l>>4;
    const int hb = hq*196;                 // padded per-group base
    const float4* wB = (const float4*)W2B + (size_t)X*3072 + l;  // [h4*64]
    float acc[2]={0,0}, s0[2]={0,0}, sna[2]={0,0}, sn[2]={0,0};
    if(!dyn){
      const float* bvp = ((w&3)==0)? sF : sB;
#pragma unroll 4
      for(int h4=0; h4<48; ++h4){
        float4 w4 = wB[h4*64];
        float4 bv = *(const float4*)(bvp + hb + h4*4);
#pragma unroll
        for(int r=0;r<2;r++){
          float4 v = *(const float4*)(&sV1[rp+r][hb + h4*4]);
          float pr;
          pr=v.x*bv.x; acc[r]=fmaf(w4.x,pr,acc[r]); s0[r]+=pr;
          pr=v.y*bv.y; acc[r]=fmaf(w4.y,pr,acc[r]); s0[r]+=pr;
          pr=v.z*bv.z; acc[r]=fmaf(w4.z,pr,acc[r]); s0[r]+=pr;
          pr=v.w*bv.w; acc[r]=fmaf(w4.w,pr,acc[r]); s0[r]+=pr;
        }
      }
    } else {
      const float (*bvp)[HPAD] = ((w&3)==2)? sAS : sAM;
#pragma unroll 4
      for(int h4=0; h4<48; ++h4){
        float4 w4 = wB[h4*64];
#pragma unroll
        for(int r=0;r<2;r++){
          float4 bv = *(const float4*)(&bvp[rp+r][hb + h4*4]);
          float4 v  = *(const float4*)(&sV1[rp+r][hb + h4*4]);
          float pr, bb;
          pr=v.x*bv.x; bb=bv.x*bv.x;
          acc[r]=fmaf(w4.x,pr,acc[r]); sna[r]=fmaf(w4.x,bb,sna[r]); s0[r]+=pr; sn[r]+=bb;
          pr=v.y*bv.y; bb=bv.y*bv.y;
          acc[r]=fmaf(w4.y,pr,acc[r]); sna[r]=fmaf(w4.y,bb,sna[r]); s0[r]+=pr; sn[r]+=bb;
          pr=v.z*bv.z; bb=bv.z*bv.z;
          acc[r]=fmaf(w4.z,pr,acc[r]); sna[r]=fmaf(w4.z,bb,sna[r]); s0[r]+=pr; sn[r]+=bb;
          pr=v.w*bv.w; bb=bv.w*bv.w;
          acc[r]=fmaf(w4.w,pr,acc[r]); sna[r]=fmaf(w4.w,bb,sna[r]); s0[r]+=pr; sn[r]+=bb;
        }
      }
    }
#pragma unroll
    for(int r=0;r<2;r++){
      acc[r]=qred_sum(acc[r]); s0[r]=qred_sum(s0[r]);
      if(dyn){ sna[r]=qred_sum(sna[r]); sn[r]=qred_sum(sn[r]); }
    }
#pragma unroll
    for(int rr=0; rr<2; ++rr){
      const int r = r0 + rp + rr;
      float* op = out + ((size_t)((b*2+side)*Ln + r))*Dn;
      if(l<16){
        float wa = fmaxf(wn[wnIdx(side,X,b,l,r)],0.f);
        float wb = dyn? fmaxf(sna[rr],0.f)
                      : fmaxf(wn[wnIdx(1-side,X,b,l,((w&3)==0? lpO:0))],0.f);
        float mul = acc[rr]/(fmaxf(sqrtf(wa),EPSF)*fmaxf(sqrtf(wb),EPSF));
        op[offs+1+l] = mul;
      }
      if(l==0){
        float nb = dyn? sqrtf(fmaxf(sn[rr],0.f)) : nOther[b*Ln + ((w&3)==0? lpO : 0)];
        float nv1 = nSelf[b*Ln+r];
        op[offs] = s0[rr]/(fmaxf(nv1,EPSF)*fmaxf(nb,EPSF));
      }
    }
  }
}

extern "C" void kernel_launch(void* const* d_in, const int* in_sizes, int n_in,
                              void* d_out, int out_size, void* d_ws, size_t ws_size,
                              hipStream_t stream) {
  const float* ctx1 = (const float*)d_in[0];
  const float* m1   = (const float*)d_in[1];
  const float* ctx2 = (const float*)d_in[2];
  const float* m2   = (const float*)d_in[3];
  const float* wff  = (const float*)d_in[4];
  const float* wfb  = (const float*)d_in[5];
  const float* wmp  = (const float*)d_in[6];
  const float* watt = (const float*)d_in[7];
  const float* wmatt= (const float*)d_in[8];
  float* out = (float*)d_out;
  float* W = (float*)d_ws;
  int* lens = (int*)(W + OFF_LENS);
  unsigned short* c2h = (unsigned short*)(W + OFF_C2H);
  unsigned short* c2l = (unsigned short*)(W + OFF_C2L);

  k_prep<<<dim3(8 + 240 + 48 + 240), 256, 0, stream>>>(m1,m2,wff,wfb,wmp,watt,wmatt,
      W+OFF_W2T, W+OFF_W2F, W+OFF_W2B, lens);
  k_rows<<<dim3(Ln/4,Bn,2), 256, 0, stream>>>(ctx1,m1,ctx2,m2, W+OFF_W2T,
      W+OFF_C1F, W+OFF_C2F, c2h, c2l, W+OFF_N1, W+OFF_N2, W+OFF_WN);
  k_mm<<<dim3(Bn, 32), 512, 0, stream>>>(W+OFF_C1F, c2h, c2l,
      W+OFF_W2F, W+OFF_WN, W+OFF_N1, W+OFF_N2, m1, m2, lens,
      W+OFF_COS, W+OFF_MVMAX, W+OFF_MVMEAN, W+OFF_PART);
  k_mm2<<<dim3((Bn*Ln*Pn)/256), 256, 0, stream>>>(W+OFF_PART, lens,
      W+OFF_MVMAX, W+OFF_MVMEAN);
  k_fin<<<dim3(16, Ln/4), 512, 0, stream>>>(W+OFF_C1F, W+OFF_C2F, W+OFF_COS,
      W+OFF_N1, W+OFF_N2, W+OFF_WN, W+OFF_W2B, W+OFF_MVMAX, W+OFF_MVMEAN,
      lens, m1, m2, out);
}

// Round 15
// 161.644 us; speedup vs baseline: 1.0571x; 1.0571x over previous
//
#include <hip/hip_runtime.h>

#define Bn 8
#define Ln 128
#define Hn 768
#define Pn 16
#define Dn 102
#define EPSF 1e-8f
#define NINF -1e30f

typedef __attribute__((ext_vector_type(8))) short bfrag8;
typedef __attribute__((ext_vector_type(4))) float f32x4;
union FragU { unsigned u[4]; bfrag8 v; };

#define MFMA16(A,B,C) __builtin_amdgcn_mfma_f32_16x16x32_bf16((A),(B),(C),0,0,0)

__device__ __forceinline__ float wred_sum(float v){
#pragma unroll
  for(int o=32;o>=1;o>>=1) v += __shfl_xor(v,o);
  return v;
}
__device__ __forceinline__ float wred_max(float v){
#pragma unroll
  for(int o=32;o>=1;o>>=1) v = fmaxf(v,__shfl_xor(v,o));
  return v;
}
__device__ __forceinline__ float qred_sum(float v){
  v += __shfl_xor(v,16);
  v += __shfl_xor(v,32);
  return v;
}

// truncation split: x = hi + lo + O(2^-16 x); packs 8 f32 -> bf16x8 hi/lo frags
__device__ __forceinline__ void split8(const float* x, FragU& H, FragU& L){
  float r[8];
#pragma unroll
  for(int q=0;q<8;q++){
    unsigned hb = __float_as_uint(x[q]) & 0xffff0000u;
    r[q] = x[q] - __uint_as_float(hb);
  }
#pragma unroll
  for(int q=0;q<4;q++){
    H.u[q] = __builtin_amdgcn_perm(__float_as_uint(x[2*q+1]), __float_as_uint(x[2*q]), 0x07060302u);
    L.u[q] = __builtin_amdgcn_perm(__float_as_uint(r[2*q+1]), __float_as_uint(r[2*q]), 0x07060302u);
  }
}

// async global->LDS DMA: per-lane global src; LDS dest = wave-uniform base + lane*16
#define GLD_LDS(gp, lp) __builtin_amdgcn_global_load_lds( \
    (const __attribute__((address_space(1))) void*)(gp), \
    (__attribute__((address_space(3))) void*)(lp), 16, 0, 0)

// ---- workspace layout (float element offsets) ----
constexpr size_t SZ_MAT   = (size_t)Bn*Ln*Hn;              // 786432
constexpr size_t OFF_C1F  = 0;
constexpr size_t OFF_C2F  = OFF_C1F + SZ_MAT;
constexpr size_t OFF_COS  = OFF_C2F + SZ_MAT;              // B*L*L
constexpr size_t OFF_N1   = OFF_COS + (size_t)Bn*Ln*Ln;    // B*L
constexpr size_t OFF_N2   = OFF_N1 + (size_t)Bn*Ln;
constexpr size_t OFF_WN   = OFF_N2 + (size_t)Bn*Ln;        // 2*5*B*P*L
constexpr size_t OFF_W2T  = OFF_WN + (size_t)2*5*Bn*Pn*Ln; // 5*H*P [X][h][p]
constexpr size_t OFF_MVMAX  = OFF_W2T + (size_t)5*Hn*Pn;   // 2*B*L*P (side0 half used)
constexpr size_t OFF_MVMEAN = OFF_MVMAX + (size_t)2*Bn*Ln*Pn;
constexpr size_t OFF_PART   = OFF_MVMEAN + (size_t)2*Bn*Ln*Pn; // B*L*P*32*2 (side1)
constexpr size_t OFF_LENS   = OFF_PART + (size_t)Bn*Ln*Pn*32*2; // 32 ints
constexpr size_t OFF_C2H    = OFF_LENS + 32;               // B*12*128*64 ushort = 393216 floats
constexpr size_t OFF_C2L    = OFF_C2H + (size_t)Bn*12*128*64/2;
constexpr size_t OFF_W2F    = OFF_C2L + (size_t)Bn*12*128*64/2; // 24*2*64*4 = 12288 floats
constexpr size_t OFF_W2B    = OFF_W2F + 12288;             // 5*48*64*4 = 61440 floats

__device__ __forceinline__ size_t wnIdx(int side,int X,int b,int p,int i){
  return ((((size_t)side*5 + X)*Bn + b)*Pn + p)*Ln + i;
}

// ---------------- k_prep: lengths + weight tables (W2T [X][h][p], W2F frag-linear mp, W2B frag-linear all-X) ----------------
__global__ __launch_bounds__(256) void k_prep(
    const float* __restrict__ m1, const float* __restrict__ m2,
    const float* __restrict__ wff, const float* __restrict__ wfb,
    const float* __restrict__ wmp, const float* __restrict__ watt,
    const float* __restrict__ wmatt,
    float* __restrict__ W2T, float* __restrict__ W2F, float* __restrict__ W2B,
    int* __restrict__ lens){
  int t = threadIdx.x;
  const float* srcs[5] = {wff,wfb,wmp,watt,wmatt};
  if(blockIdx.x < 8){
    int b = blockIdx.x;
    __shared__ int cnt[2];
    if(t<2) cnt[t]=0;
    __syncthreads();
    if(t<Ln){
      if(m1[b*Ln+t]>0.5f) atomicAdd(&cnt[0],1);
      if(m2[b*Ln+t]>0.5f) atomicAdd(&cnt[1],1);
    }
    __syncthreads();
    if(t==0){
      lens[b]=cnt[0]; lens[8+b]=cnt[1];
      lens[16+b]=max(cnt[0]-1,0); lens[24+b]=max(cnt[1]-1,0);
    }
  } else if(blockIdx.x < 248){
    int idx = (blockIdx.x-8)*256 + t;     // < 5*768*16 = 61440
    int X = idx/(Pn*Hn);
    int r = idx%(Pn*Hn);
    int h = r/Pn, p = r%Pn;
    float w = srcs[X][p*Hn+h];
    W2T[idx] = w*w;                        // layout [X][h][p]
  } else if(blockIdx.x < 296){
    // W2F: fragment-linear fp32 w2 for mp: [ksg 24][half 2][64 lanes][4]
    int idx = (blockIdx.x-248)*256 + t;    // < 12288
    int ksg = idx>>9;
    int r   = idx&511;
    int half= r>>8;
    int li  = (r>>2)&63;
    int e4  = r&3;
    int h = ksg*32 + half*16 + ((li>>4)<<2) + e4;
    int p = li&15;
    float w = wmp[p*Hn+h];
    W2F[idx] = w*w;
  } else {
    // W2B: k_fin Phase-B frag-linear: [X 5][hh4 48][lane 64][4]
    // entry = w2[p = lane&15][h = (lane>>4)*192 + hh4*4 + e]
    int idx = (blockIdx.x-296)*256 + t;    // < 61440
    int X   = idx/12288;
    int r   = idx%12288;
    int hh4 = r>>8;
    int li  = (r>>2)&63;
    int e   = r&3;
    int h = (li>>4)*192 + hh4*4 + e;
    int p = li&15;
    float w = srcs[X][p*Hn+h];
    W2B[idx] = w*w;
  }
}

// ---------------- k_rows: 4 rows/block; masked rows + norms + bf16 split + p-in-thread weighted norms ----------------
// grid (Ln/4, Bn, 2), 256 thr.
__global__ __launch_bounds__(256) void k_rows(
    const float* __restrict__ ctx1, const float* __restrict__ m1,
    const float* __restrict__ ctx2, const float* __restrict__ m2,
    const float* __restrict__ W2T,
    float* __restrict__ c1f, float* __restrict__ c2f,
    unsigned short* __restrict__ c2h, unsigned short* __restrict__ c2l,
    float* __restrict__ n1, float* __restrict__ n2, float* __restrict__ wn){
  const int i0 = blockIdx.x*4, b = blockIdx.y, side = blockIdx.z;
  const float* ctx = side? ctx2 : ctx1;
  const float* msk = side? m2 : m1;
  float* dst = side? c2f : c1f;
  float* nD  = side? n2 : n1;
  const int t = threadIdx.x, w = t>>6, l = t&63;

  __shared__ float red4[4][4];
  __shared__ float redX[4][4][16];   // [wave][pq][r*4+pi]
  __shared__ float mkS[4];

  if(t<4) mkS[t] = msk[b*Ln+i0+t];

  // ---- Phase 1: masked write-out + bf16 split + norms (4 rows) ----
#pragma unroll
  for(int r=0;r<4;r++){
    const int i = i0+r;
    const float mk = msk[b*Ln+i];
    const size_t base = ((size_t)(b*Ln+i))*Hn;
    float ss = 0.f;
#pragma unroll
    for(int k=0;k<3;k++){
      float x = ctx[base + t + 256*k]*mk;
      dst[base + t + 256*k] = x;
      ss = fmaf(x,x,ss);
      if(side==1){
        int h = t+256*k;
        int kc = h>>6, hw = h&63, u = hw>>2, e = hw&3;
        int pos = ((u ^ (i&15))<<2) + e;
        size_t o = ((size_t)(b*12+kc)*128 + i)*64 + pos;
        unsigned hb = __float_as_uint(x) & 0xffff0000u;
        float rem = x - __uint_as_float(hb);
        c2h[o] = (unsigned short)(hb>>16);
        c2l[o] = (unsigned short)(__float_as_uint(rem)>>16);
      }
    }
    ss = wred_sum(ss);
    if(l==0) red4[r][w]=ss;
  }
  __syncthreads();
  if(t<4) nD[b*Ln+i0+t] = sqrtf(fmaxf(red4[t][0]+red4[t][1]+red4[t][2]+red4[t][3],0.f));

  // ---- Phase 2: weighted norms, thread = (hc: h-block of 12, pq: 4 p's) ----
  const int pq = t&3, hc = t>>2;
  const int h0 = hc*12;
  float v2r[4][12];
#pragma unroll
  for(int r=0;r<4;r++){
    const float mk = mkS[r];
    const float* src = ctx + ((size_t)(b*Ln+i0+r))*Hn + h0;
#pragma unroll
    for(int q=0;q<3;q++){
      float4 xv = *(const float4*)(src + q*4);
      v2r[r][q*4+0]=xv.x*xv.x*mk; v2r[r][q*4+1]=xv.y*xv.y*mk;
      v2r[r][q*4+2]=xv.z*xv.z*mk; v2r[r][q*4+3]=xv.w*xv.w*mk;
    }
  }
  for(int X=0;X<5;++X){
    float acc[4][4];
#pragma unroll
    for(int r=0;r<4;r++){ acc[r][0]=0.f; acc[r][1]=0.f; acc[r][2]=0.f; acc[r][3]=0.f; }
    const float* wb = W2T + (size_t)X*Hn*Pn + pq*4;
#pragma unroll
    for(int h=0;h<12;h++){
      float4 w4 = *(const float4*)(wb + (size_t)(h0+h)*Pn);
#pragma unroll
      for(int r=0;r<4;r++){
        acc[r][0]=fmaf(w4.x,v2r[r][h],acc[r][0]);
        acc[r][1]=fmaf(w4.y,v2r[r][h],acc[r][1]);
        acc[r][2]=fmaf(w4.z,v2r[r][h],acc[r][2]);
        acc[r][3]=fmaf(w4.w,v2r[r][h],acc[r][3]);
      }
    }
#pragma unroll
    for(int r=0;r<4;r++)
#pragma unroll
      for(int pi=0;pi<4;pi++){
        float v = acc[r][pi];
        v += __shfl_xor(v,4); v += __shfl_xor(v,8);
        v += __shfl_xor(v,16); v += __shfl_xor(v,32);
        acc[r][pi]=v;
      }
    if(l<4){
#pragma unroll
      for(int r=0;r<4;r++)
#pragma unroll
        for(int pi=0;pi<4;pi++) redX[w][l][r*4+pi]=acc[r][pi];
    }
    __syncthreads();
    if(t<64){
      int r = t>>4, p = t&15;
      int pqi = p>>2, pii = p&3;
      float s = redX[0][pqi][r*4+pii]+redX[1][pqi][r*4+pii]
               +redX[2][pqi][r*4+pii]+redX[3][pqi][r*4+pii];
      wn[wnIdx(side,X,b,p,i0+r)] = s;
    }
    __syncthreads();
  }
}

// ---------------- k_mm: MFMA split-bf16 e-tensor + cos ----------------
// grid (Bn, 32): block = (b, 4 i, all 128 j). 512 thr = 8 waves (jtp:4, ihalf:2).
__global__ __launch_bounds__(512) void k_mm(
    const float* __restrict__ c1f,
    const unsigned short* __restrict__ c2h, const unsigned short* __restrict__ c2l,
    const float* __restrict__ W2F, const float* __restrict__ WN,
    const float* __restrict__ n1, const float* __restrict__ n2,
    const float* __restrict__ m1, const float* __restrict__ m2,
    const int* __restrict__ lens,
    float* __restrict__ cosM,
    float* __restrict__ mvmax, float* __restrict__ mvmean,
    float* __restrict__ part){
  const int b = blockIdx.x, ig = blockIdx.y, ibase = ig*4;
  const int t = threadIdx.x, l = t&63;
  const int wid = __builtin_amdgcn_readfirstlane(t>>6);
  const int jtp = wid&3, ihalf = wid>>2;
  const int p = l&15, g4 = l>>4;

  __shared__ __align__(16) unsigned short sB2h[2][128][64];  // 32 KB
  __shared__ __align__(16) unsigned short sB2l[2][128][64];  // 32 KB
  __shared__ __align__(16) float sw2[2][1024];               // 8 KB [ks][half][64][4]
  __shared__ __align__(16) float sa[2][4][64];               // 2 KB (swizzled units)
  __shared__ float sm2s[Ln];
  __shared__ float red0[2][4][2][16][2];                     // [ihalf][jtp][ii][p][M,S]

  const size_t c2elem = (size_t)b*12*8192;   // ushort elements to chunk 0 of b

  // ---- prologue: DMA chunk 0 (B2 hi/lo, w2f), stage sm2 + a(kc0) ----
  {
#pragma unroll
    for(int k=0;k<2;k++){
      GLD_LDS((const char*)c2h + c2elem*2 + (2*wid+k)*1024 + l*16,
              (char*)&sB2h[0][0][0] + (2*wid+k)*1024);
      GLD_LDS((const char*)c2l + c2elem*2 + (2*wid+k)*1024 + l*16,
              (char*)&sB2l[0][0][0] + (2*wid+k)*1024);
    }
    if(wid>=4){
      int q = wid-4;
      GLD_LDS((const char*)W2F + q*1024 + l*16,
              (char*)&sw2[0][0] + q*1024);
    }
    if(t<Ln) sm2s[t] = m2[b*Ln+t];
    if(t<64){
      int row = t>>4, u = t&15;
      float4 av = *(const float4*)(c1f + ((size_t)(b*Ln+ibase+row))*Hn + u*4);
      *(float4*)&sa[0][row][(u ^ (row&3))<<2] = av;
    }
  }
  __syncthreads();

  f32x4 accE[2][2]; f32x4 accC[2];
#pragma unroll
  for(int q=0;q<2;q++){
    accC[q] = (f32x4){0.f,0.f,0.f,0.f};
#pragma unroll
    for(int ii=0;ii<2;ii++) accE[q][ii] = (f32x4){0.f,0.f,0.f,0.f};
  }

  for(int c=0; c<12; ++c){
    const int cur = c&1, nxt = cur^1;
    const bool more = (c+1<12);
    float4 aN;
    if(more){
      const size_t cb2 = (c2elem + (size_t)(c+1)*8192)*2;   // bytes
#pragma unroll
      for(int k=0;k<2;k++){
        GLD_LDS((const char*)c2h + cb2 + (2*wid+k)*1024 + l*16,
                (char*)&sB2h[nxt][0][0] + (2*wid+k)*1024);
        GLD_LDS((const char*)c2l + cb2 + (2*wid+k)*1024 + l*16,
                (char*)&sB2l[nxt][0][0] + (2*wid+k)*1024);
      }
      if(wid>=4){
        int q = wid-4;
        GLD_LDS((const char*)W2F + (c+1)*4096 + q*1024 + l*16,
                (char*)&sw2[nxt][0] + q*1024);
      }
      if(t<64){
        int row = t>>4, u = t&15;
        aN = *(const float4*)(c1f + ((size_t)(b*Ln+ibase+row))*Hn + (c+1)*64 + u*4);
      }
    }
#pragma unroll
    for(int ks=0; ks<2; ++ks){
      f32x4 w20 = *(const f32x4*)&sw2[cur][(ks*2+0)*256 + (l<<2)];
      f32x4 w21 = *(const f32x4*)&sw2[cur][(ks*2+1)*256 + (l<<2)];
      FragU Bh[2], Bl[2];
#pragma unroll
      for(int q=0;q<2;q++){
        int jt = jtp + 4*q;
        int j  = jt*16 + p;
        const char* bh = (const char*)&sB2h[cur][0][0] + j*128;
        const char* bl = (const char*)&sB2l[cur][0][0] + j*128;
        int u1 = (ks*8 + g4)     ^ (j&15);
        int u2 = (ks*8 + 4 + g4) ^ (j&15);
        uint2 h0 = *(const uint2*)(bh + (u1<<3));
        uint2 h1 = *(const uint2*)(bh + (u2<<3));
        uint2 l0 = *(const uint2*)(bl + (u1<<3));
        uint2 l1 = *(const uint2*)(bl + (u2<<3));
        Bh[q].u[0]=h0.x; Bh[q].u[1]=h0.y; Bh[q].u[2]=h1.x; Bh[q].u[3]=h1.y;
        Bl[q].u[0]=l0.x; Bl[q].u[1]=l0.y; Bl[q].u[2]=l1.x; Bl[q].u[3]=l1.y;
      }
      if(ihalf==0){
        int ar = p&3;
        const float* sar = &sa[cur][ar][0];
        f32x4 a0 = *(const f32x4*)(sar + (((ks*8+g4)  ^ar)<<2));
        f32x4 a1 = *(const f32x4*)(sar + (((ks*8+4+g4)^ar)<<2));
        float xv[8] = {a0[0],a0[1],a0[2],a0[3], a1[0],a1[1],a1[2],a1[3]};
        FragU Ah, Al; split8(xv, Ah, Al);
#pragma unroll
        for(int q=0;q<2;q++){
          accC[q] = MFMA16(Bh[q].v, Ah.v, accC[q]);
          accC[q] = MFMA16(Bh[q].v, Al.v, accC[q]);
          accC[q] = MFMA16(Bl[q].v, Ah.v, accC[q]);
        }
      }
#pragma unroll
      for(int ii=0;ii<2;ii++){
        int row = ihalf*2+ii;
        const float* sar = &sa[cur][row][0];
        f32x4 a0 = *(const f32x4*)(sar + (((ks*8+g4)  ^(row&3))<<2));
        f32x4 a1 = *(const f32x4*)(sar + (((ks*8+4+g4)^(row&3))<<2));
        float xv[8] = {a0[0]*w20[0], a0[1]*w20[1], a0[2]*w20[2], a0[3]*w20[3],
                       a1[0]*w21[0], a1[1]*w21[1], a1[2]*w21[2], a1[3]*w21[3]};
        FragU Ah, Al; split8(xv, Ah, Al);
#pragma unroll
        for(int q=0;q<2;q++){
          accE[q][ii] = MFMA16(Bh[q].v, Ah.v, accE[q][ii]);
          accE[q][ii] = MFMA16(Bh[q].v, Al.v, accE[q][ii]);
          accE[q][ii] = MFMA16(Bl[q].v, Ah.v, accE[q][ii]);
        }
      }
    }
    if(more && t<64){
      int row = t>>4, u = t&15;
      *(float4*)&sa[nxt][row][(u ^ (row&3))<<2] = aN;
    }
    __syncthreads();   // one barrier/chunk: readers done + next DMA drained
  }

  // ---- epilogue: normalize, side0 (final), side1 (partial->part), cos ----
  const int len2 = min(max(lens[8+b],1),Ln);
  float sq1[2][4];
#pragma unroll
  for(int q=0;q<2;q++){
    int jt = jtp+4*q;
#pragma unroll
    for(int r=0;r<4;r++){
      int j = jt*16 + g4*4 + r;
      sq1[q][r] = sqrtf(fmaxf(WN[wnIdx(1,2,b,p,j)],0.f));
    }
  }
  float s1M[2][4], s1S[2][4];
#pragma unroll
  for(int q=0;q<2;q++)
#pragma unroll
    for(int r=0;r<4;r++){ s1M[q][r]=NINF; s1S[q][r]=0.f; }

#pragma unroll
  for(int ii=0;ii<2;ii++){
    int iR = ibase + ihalf*2 + ii;
    float sr = sqrtf(fmaxf(WN[wnIdx(0,2,b,p,iR)],0.f));
    float mr = m1[b*Ln+iR];
    float vmax=NINF, vsum=0.f;
#pragma unroll
    for(int q=0;q<2;q++){
      int jt = jtp+4*q;
#pragma unroll
      for(int r=0;r<4;r++){
        int j = jt*16 + g4*4 + r;
        float ev = accE[q][ii][r] / fmaxf(sr*sq1[q][r], EPSF);
        if(sm2s[j]!=0.f){ vmax=fmaxf(vmax,ev); vsum+=ev; }
        if(mr!=0.f){ s1M[q][r]=fmaxf(s1M[q][r],ev); s1S[q][r]+=ev; }
      }
    }
    vmax = fmaxf(vmax, __shfl_xor(vmax,16)); vmax = fmaxf(vmax, __shfl_xor(vmax,32));
    vsum += __shfl_xor(vsum,16); vsum += __shfl_xor(vsum,32);
    if(l<16){ red0[ihalf][jtp][ii][l][0]=vmax; red0[ihalf][jtp][ii][l][1]=vsum; }
  }
  float* red1 = (float*)&sB2h[0][0][0];   // alias (sB2 dead), 16 KB
  if(ihalf==1){
#pragma unroll
    for(int q=0;q<2;q++)
#pragma unroll
      for(int r=0;r<4;r++){
        int idx = (((jtp*2+q)*64 + l)*4 + r)*2;
        red1[idx]   = s1M[q][r];
        red1[idx+1] = s1S[q][r];
      }
  }
  __syncthreads();
  if(t<64){
    int ih_=t>>5, ii_=(t>>4)&1, p_=t&15;
    float M=NINF,S=0.f;
#pragma unroll
    for(int jq=0;jq<4;jq++){ M=fmaxf(M,red0[ih_][jq][ii_][p_][0]); S+=red0[ih_][jq][ii_][p_][1]; }
    int iR = ibase + ih_*2 + ii_;
    size_t o = ((size_t)(b*Ln+iR))*Pn + p_;
    mvmax[o]=M; mvmean[o]=S/(float)len2;   // side0: final (all j in block)
  }
  if(ihalf==0){
#pragma unroll
    for(int q=0;q<2;q++){
      int jt = jtp+4*q;
#pragma unroll
      for(int r=0;r<4;r++){
        int j = jt*16 + g4*4 + r;
        int idx = (((jtp*2+q)*64 + l)*4 + r)*2;
        float M = fmaxf(s1M[q][r], red1[idx]);
        float S = s1S[q][r] + red1[idx+1];
        size_t o = ((((size_t)(b*Ln+j))*Pn + p)*32 + ig)*2;
        part[o]=M; part[o+1]=S;
        float nj = fmaxf(n2[b*Ln+j], EPSF);
        if(p<4){
          int iR = ibase + p;
          float ni = fmaxf(n1[b*Ln+iR], EPSF);
          cosM[((size_t)(b*Ln+iR))*Ln + j] = accC[q][r]/(ni*nj);
        }
      }
    }
  }
}

// ---------------- k_fin: attention + all 102 features; 4 rows/block (R12 winner) ----------------
// grid (16, Ln/4): x = side*8+b → XCD = b
// R12-R14 record: k_fin pinned 44-52µs across 4 geometries; R12's 4-row/256-thr
// form (44.2µs) is the winner — the floor is the dependent L2 load chain in the
// attention loop, not blocking. This round: revert to R12 + fold k_mm2 inline
// (side-1 Phase C reduces `part` directly; part is L2-warm on the same XCD).
#define HPAD 784              // 768 + 4*4
__global__ __launch_bounds__(256) void k_fin(
    const float* __restrict__ c1f, const float* __restrict__ c2f,
    const float* __restrict__ cosM,
    const float* __restrict__ n1, const float* __restrict__ n2,
    const float* __restrict__ wn, const float* __restrict__ W2B,
    const float* __restrict__ mvmax, const float* __restrict__ mvmean,
    const float* __restrict__ part,
    const int* __restrict__ lens,
    const float* __restrict__ m1, const float* __restrict__ m2,
    float* __restrict__ out){
  const int x = blockIdx.x, side = x>>3, b = x&7;
  const int r0 = blockIdx.y*4;
  const int t = threadIdx.x, w = t>>6, l = t&63;
  const float* selfF  = side? c2f : c1f;
  const float* otherF = side? c1f : c2f;
  const float* nSelf  = side? n2 : n1;
  const float* nOther = side? n1 : n2;
  const float* mInner = side? m1 : m2;
  const float* mSelfm = side? m2 : m1;
  int lenI = side? lens[b]    : lens[8+b];
  int lpO  = side? lens[16+b] : lens[24+b];
  lenI = min(max(lenI,1),Ln);
  lpO  = min(max(lpO,0),Ln-1);

  __shared__ float cS[4*Ln];
  __shared__ float mS[Ln];
  __shared__ __align__(16) float sV1[4][HPAD];
  __shared__ __align__(16) float sF[HPAD], sB[HPAD];
  __shared__ __align__(16) float sAS[4][HPAD], sAM[4][HPAD];
  __shared__ float redm[4][4], reds[4][4];

  // ---- stage (padded: float4-unit q -> q + q/48; scalar h -> h + 4*(h/192)) ----
  {
    if(side==0){
      const float* crow = cosM + ((size_t)(b*Ln+r0))*Ln;
      for(int idx=t; idx<4*Ln; idx+=256) cS[idx]=crow[idx];
    } else {
      for(int idx=t; idx<4*Ln; idx+=256){
        int jj = idx&127, rp = idx>>7;   // transposed: cos^T[r][j] = cosM[j][r]
        cS[rp*Ln+jj] = cosM[((size_t)(b*Ln+jj))*Ln + r0+rp];
      }
    }
    if(t<Ln) mS[t]=mInner[b*Ln+t];
    const float4* s4 = (const float4*)(selfF + ((size_t)(b*Ln+r0))*Hn);
    for(int idx=t; idx<4*Hn/4; idx+=256){
      int row = idx/192, q = idx - row*192;
      ((float4*)&sV1[row][0])[q + q/48] = s4[idx];
    }
    const float4* f4 = (const float4*)(otherF + ((size_t)(b*Ln+lpO))*Hn);
    const float4* b4 = (const float4*)(otherF + ((size_t)(b*Ln))*Hn);
    if(t<Hn/4){
      ((float4*)sF)[t + t/48]=f4[t];
      ((float4*)sB)[t + t/48]=b4[t];
    }
  }
  __syncthreads();

  // ---- attention accumulation (4 rows, h = 3t..3t+2); jj < lenI only ----
  float aS[4][3], aM[4][3];
#pragma unroll
  for(int r=0;r<4;r++)
#pragma unroll
    for(int k=0;k<3;k++){ aS[r][k]=0.f; aM[r][k]=NINF; }
  {
    const float* src = otherF + (size_t)b*Ln*Hn;
#pragma unroll 2
    for(int jj=0; jj<lenI; ++jj){        // jj<lenI => mS[jj]!=0 (prefix mask)
      float3 vk = ((const float3*)(src + (size_t)jj*Hn))[t];
      float c0=cS[jj], c1v=cS[Ln+jj], c2v=cS[2*Ln+jj], c3v=cS[3*Ln+jj];
      aS[0][0]=fmaf(vk.x,c0 ,aS[0][0]); aS[0][1]=fmaf(vk.y,c0 ,aS[0][1]); aS[0][2]=fmaf(vk.z,c0 ,aS[0][2]);
      aS[1][0]=fmaf(vk.x,c1v,aS[1][0]); aS[1][1]=fmaf(vk.y,c1v,aS[1][1]); aS[1][2]=fmaf(vk.z,c1v,aS[1][2]);
      aS[2][0]=fmaf(vk.x,c2v,aS[2][0]); aS[2][1]=fmaf(vk.y,c2v,aS[2][1]); aS[2][2]=fmaf(vk.z,c2v,aS[2][2]);
      aS[3][0]=fmaf(vk.x,c3v,aS[3][0]); aS[3][1]=fmaf(vk.y,c3v,aS[3][1]); aS[3][2]=fmaf(vk.z,c3v,aS[3][2]);
      aM[0][0]=fmaxf(aM[0][0],vk.x*c0 ); aM[0][1]=fmaxf(aM[0][1],vk.y*c0 ); aM[0][2]=fmaxf(aM[0][2],vk.z*c0 );
      aM[1][0]=fmaxf(aM[1][0],vk.x*c1v); aM[1][1]=fmaxf(aM[1][1],vk.y*c1v); aM[1][2]=fmaxf(aM[1][2],vk.z*c1v);
      aM[2][0]=fmaxf(aM[2][0],vk.x*c2v); aM[2][1]=fmaxf(aM[2][1],vk.y*c2v); aM[2][2]=fmaxf(aM[2][2],vk.z*c2v);
      aM[3][0]=fmaxf(aM[3][0],vk.x*c3v); aM[3][1]=fmaxf(aM[3][1],vk.y*c3v); aM[3][2]=fmaxf(aM[3][2],vk.z*c3v);
    }
  }

  // ---- softmax over h (4 rows) ----
  {
#pragma unroll
    for(int r=0;r<4;r++){
      float lm = fmaxf(fmaxf(aS[r][0],aS[r][1]),aS[r][2]);
      lm = wred_max(lm);
      if(l==0) redm[r][w]=lm;
    }
  }
  __syncthreads();
  float bm[4];
#pragma unroll
  for(int r=0;r<4;r++)
    bm[r] = fmaxf(fmaxf(redm[r][0],redm[r][1]),fmaxf(redm[r][2],redm[r][3]));
  float ev[4][3];
  {
#pragma unroll
    for(int r=0;r<4;r++){
      float es=0.f;
#pragma unroll
      for(int k=0;k<3;k++){ ev[r][k]=expf(aS[r][k]-bm[r]); es+=ev[r][k]; }
      es = wred_sum(es);
      if(l==0) reds[r][w]=es;
    }
  }
  __syncthreads();
  {
    const float u = 1.f/(float)Hn;
#pragma unroll
    for(int r=0;r<4;r++){
      float smr = mSelfm[b*Ln+r0+r];
      float bs = reds[r][0]+reds[r][1]+reds[r][2]+reds[r][3];
      float inv = 1.f/fmaxf(bs,EPSF);
#pragma unroll
      for(int k=0;k<3;k++){
        int h = 3*t+k;
        int hi = h + ((h/192)<<2);
        sAS[r][hi] = (smr!=0.f)? ev[r][k]*inv : u;
        sAM[r][hi] = aM[r][k];
      }
    }
  }
  __syncthreads();

  // ---- Phase A (all 4 waves, row = w) + Phase C (t<128; side1 reduces part inline) ----
  {
    int rr = w;
    float cmx=NINF, csm=0.f;
    float ca = cS[rr*Ln + l], cb = cS[rr*Ln + l + 64];
    if(mS[l]!=0.f){ cmx=ca; csm=ca; }
    if(mS[l+64]!=0.f){ cmx=fmaxf(cmx,cb); csm+=cb; }
    cmx = wred_max(cmx); csm = wred_sum(csm);
    if(l==0){
      float* op = out + ((size_t)((b*2+side)*Ln + r0+rr))*Dn;
      op[0] = cmx;
      op[1] = csm/(float)lenI;
    }
  }
  if(t<128){
    int rr = t>>5, qq = t&31, p = qq&15;
    float* op = out + ((size_t)((b*2+side)*Ln + r0+rr))*Dn;
    if(side==0){
      size_t o = ((size_t)(b*Ln + r0+rr))*Pn + p;        // side0: final from k_mm
      if(qq<16) op[36+p] = mvmax[o];
      else      op[52+p] = mvmean[o];
    } else {
      // side1: reduce 32 i-tile partials inline (was k_mm2); L2-warm, same XCD
      const float4* q4 = (const float4*)(part + (((size_t)(b*Ln + r0+rr))*Pn + p)*64);
      float mx = NINF, sm = 0.f;
#pragma unroll
      for(int k=0;k<16;k++){
        float4 v = q4[k];
        mx = fmaxf(mx, fmaxf(v.x, v.z));
        sm += v.y + v.w;
      }
      if(qq<16) op[36+p] = mx;
      else      op[52+p] = sm/(float)lenI;               // lenI == clamped lens[b]
    }
  }

  // ---- Phase B: wave w handles mi=w for 4 rows; lane = (p, hq) ----
  {
    const int Xids[4] = {0,1,3,4};
    const int offS[4] = {2,19,68,85};
    const int X = Xids[w], offs = offS[w];
    const bool dyn = (w>=2);
    const int p = l&15, hq = l>>4;
    const int hb = hq*196;                  // padded per-group base
    const float4* wB = (const float4*)W2B + (size_t)X*3072 + l;  // [h4*64]
    float acc[4]={0,0,0,0}, s0[4]={0,0,0,0};
    float sna[4]={0,0,0,0}, sn[4]={0,0,0,0};
    if(!dyn){
      const float* bvp = (w==0)? sF : sB;
#pragma unroll 4
      for(int h4=0; h4<48; ++h4){
        float4 w4 = wB[h4*64];
        float4 bv = *(const float4*)(bvp + hb + h4*4);
#pragma unroll
        for(int r=0;r<4;r++){
          float4 v = *(const float4*)(&sV1[r][hb + h4*4]);
          float pr;
          pr=v.x*bv.x; acc[r]=fmaf(w4.x,pr,acc[r]); s0[r]+=pr;
          pr=v.y*bv.y; acc[r]=fmaf(w4.y,pr,acc[r]); s0[r]+=pr;
          pr=v.z*bv.z; acc[r]=fmaf(w4.z,pr,acc[r]); s0[r]+=pr;
          pr=v.w*bv.w; acc[r]=fmaf(w4.w,pr,acc[r]); s0[r]+=pr;
        }
      }
    } else {
      const float (*bvp)[HPAD] = (w==2)? sAS : sAM;
#pragma unroll 2
      for(int h4=0; h4<48; ++h4){
        float4 w4 = wB[h4*64];
#pragma unroll
        for(int r=0;r<4;r++){
          float4 bv = *(const float4*)(&bvp[r][hb + h4*4]);
          float4 v  = *(const float4*)(&sV1[r][hb + h4*4]);
          float pr, bb;
          pr=v.x*bv.x; bb=bv.x*bv.x;
          acc[r]=fmaf(w4.x,pr,acc[r]); sna[r]=fmaf(w4.x,bb,sna[r]); s0[r]+=pr; sn[r]+=bb;
          pr=v.y*bv.y; bb=bv.y*bv.y;
          acc[r]=fmaf(w4.y,pr,acc[r]); sna[r]=fmaf(w4.y,bb,sna[r]); s0[r]+=pr; sn[r]+=bb;
          pr=v.z*bv.z; bb=bv.z*bv.z;
          acc[r]=fmaf(w4.z,pr,acc[r]); sna[r]=fmaf(w4.z,bb,sna[r]); s0[r]+=pr; sn[r]+=bb;
          pr=v.w*bv.w; bb=bv.w*bv.w;
          acc[r]=fmaf(w4.w,pr,acc[r]); sna[r]=fmaf(w4.w,bb,sna[r]); s0[r]+=pr; sn[r]+=bb;
        }
      }
    }
#pragma unroll
    for(int r=0;r<4;r++){
      acc[r]=qred_sum(acc[r]); s0[r]=qred_sum(s0[r]);
      if(dyn){ sna[r]=qred_sum(sna[r]); sn[r]=qred_sum(sn[r]); }
    }
#pragma unroll
    for(int rr=0; rr<4; ++rr){
      const int r = r0+rr;
      float* op = out + ((size_t)((b*2+side)*Ln + r))*Dn;
      if(l<16){
        float wa = fmaxf(wn[wnIdx(side,X,b,l,r)],0.f);
        float wb = dyn? fmaxf(sna[rr],0.f)
                      : fmaxf(wn[wnIdx(1-side,X,b,l,(w==0? lpO:0))],0.f);
        float mul = acc[rr]/(fmaxf(sqrtf(wa),EPSF)*fmaxf(sqrtf(wb),EPSF));
        op[offs+1+l] = mul;
      }
      if(l==0){
        float nb = dyn? sqrtf(fmaxf(sn[rr],0.f)) : nOther[b*Ln + (w==0? lpO : 0)];
        float nv1 = nSelf[b*Ln+r];
        op[offs] = s0[rr]/(fmaxf(nv1,EPSF)*fmaxf(nb,EPSF));
      }
    }
  }
}

extern "C" void kernel_launch(void* const* d_in, const int* in_sizes, int n_in,
                              void* d_out, int out_size, void* d_ws, size_t ws_size,
                              hipStream_t stream) {
  const float* ctx1 = (const float*)d_in[0];
  const float* m1   = (const float*)d_in[1];
  const float* ctx2 = (const float*)d_in[2];
  const float* m2   = (const float*)d_in[3];
  const float* wff  = (const float*)d_in[4];
  const float* wfb  = (const float*)d_in[5];
  const float* wmp  = (const float*)d_in[6];
  const float* watt = (const float*)d_in[7];
  const float* wmatt= (const float*)d_in[8];
  float* out = (float*)d_out;
  float* W = (float*)d_ws;
  int* lens = (int*)(W + OFF_LENS);
  unsigned short* c2h = (unsigned short*)(W + OFF_C2H);
  unsigned short* c2l = (unsigned short*)(W + OFF_C2L);

  k_prep<<<dim3(8 + 240 + 48 + 240), 256, 0, stream>>>(m1,m2,wff,wfb,wmp,watt,wmatt,
      W+OFF_W2T, W+OFF_W2F, W+OFF_W2B, lens);
  k_rows<<<dim3(Ln/4,Bn,2), 256, 0, stream>>>(ctx1,m1,ctx2,m2, W+OFF_W2T,
      W+OFF_C1F, W+OFF_C2F, c2h, c2l, W+OFF_N1, W+OFF_N2, W+OFF_WN);
  k_mm<<<dim3(Bn, 32), 512, 0, stream>>>(W+OFF_C1F, c2h, c2l,
      W+OFF_W2F, W+OFF_WN, W+OFF_N1, W+OFF_N2, m1, m2, lens,
      W+OFF_COS, W+OFF_MVMAX, W+OFF_MVMEAN, W+OFF_PART);
  k_fin<<<dim3(16, Ln/4), 256, 0, stream>>>(W+OFF_C1F, W+OFF_C2F, W+OFF_COS,
      W+OFF_N1, W+OFF_N2, W+OFF_WN, W+OFF_W2B, W+OFF_MVMAX, W+OFF_MVMEAN,
      W+OFF_PART, lens, m1, m2, out);
}

// Round 16
// 160.732 us; speedup vs baseline: 1.0631x; 1.0057x over previous
//
#include <hip/hip_runtime.h>

#define Bn 8
#define Ln 128
#define Hn 768
#define Pn 16
#define Dn 102
#define EPSF 1e-8f
#define NINF -1e30f

typedef __attribute__((ext_vector_type(8))) short bfrag8;
typedef __attribute__((ext_vector_type(4))) float f32x4;
union FragU { unsigned u[4]; bfrag8 v; };

#define MFMA16(A,B,C) __builtin_amdgcn_mfma_f32_16x16x32_bf16((A),(B),(C),0,0,0)

__device__ __forceinline__ float wred_sum(float v){
#pragma unroll
  for(int o=32;o>=1;o>>=1) v += __shfl_xor(v,o);
  return v;
}
__device__ __forceinline__ float wred_max(float v){
#pragma unroll
  for(int o=32;o>=1;o>>=1) v = fmaxf(v,__shfl_xor(v,o));
  return v;
}
__device__ __forceinline__ float qred_sum(float v){
  v += __shfl_xor(v,16);
  v += __shfl_xor(v,32);
  return v;
}

// truncation split: x = hi + lo + O(2^-16 x); packs 8 f32 -> bf16x8 hi/lo frags
__device__ __forceinline__ void split8(const float* x, FragU& H, FragU& L){
  float r[8];
#pragma unroll
  for(int q=0;q<8;q++){
    unsigned hb = __float_as_uint(x[q]) & 0xffff0000u;
    r[q] = x[q] - __uint_as_float(hb);
  }
#pragma unroll
  for(int q=0;q<4;q++){
    H.u[q] = __builtin_amdgcn_perm(__float_as_uint(x[2*q+1]), __float_as_uint(x[2*q]), 0x07060302u);
    L.u[q] = __builtin_amdgcn_perm(__float_as_uint(r[2*q+1]), __float_as_uint(r[2*q]), 0x07060302u);
  }
}

// async global->LDS DMA: per-lane global src; LDS dest = wave-uniform base + lane*16
#define GLD_LDS(gp, lp) __builtin_amdgcn_global_load_lds( \
    (const __attribute__((address_space(1))) void*)(gp), \
    (__attribute__((address_space(3))) void*)(lp), 16, 0, 0)

// ---- workspace layout (float element offsets) ----
constexpr size_t SZ_MAT   = (size_t)Bn*Ln*Hn;              // 786432
constexpr size_t OFF_C1F  = 0;
constexpr size_t OFF_C2F  = OFF_C1F + SZ_MAT;
constexpr size_t OFF_COS  = OFF_C2F + SZ_MAT;              // B*L*L
constexpr size_t OFF_N1   = OFF_COS + (size_t)Bn*Ln*Ln;    // B*L
constexpr size_t OFF_N2   = OFF_N1 + (size_t)Bn*Ln;
constexpr size_t OFF_WN   = OFF_N2 + (size_t)Bn*Ln;        // 2*5*B*P*L
constexpr size_t OFF_W2T  = OFF_WN + (size_t)2*5*Bn*Pn*Ln; // 5*H*P [X][h][p]
constexpr size_t OFF_MVMAX  = OFF_W2T + (size_t)5*Hn*Pn;   // 2*B*L*P
constexpr size_t OFF_MVMEAN = OFF_MVMAX + (size_t)2*Bn*Ln*Pn;
constexpr size_t OFF_PART   = OFF_MVMEAN + (size_t)2*Bn*Ln*Pn; // B*L*P*32*2 (side1)
constexpr size_t OFF_LENS   = OFF_PART + (size_t)Bn*Ln*Pn*32*2; // 32 ints
constexpr size_t OFF_C2H    = OFF_LENS + 32;               // B*12*128*64 ushort = 393216 floats
constexpr size_t OFF_C2L    = OFF_C2H + (size_t)Bn*12*128*64/2;
constexpr size_t OFF_W2F    = OFF_C2L + (size_t)Bn*12*128*64/2; // 24*2*64*4 = 12288 floats
constexpr size_t OFF_W2B    = OFF_W2F + 12288;             // 5*48*64*4 = 61440 floats

__device__ __forceinline__ size_t wnIdx(int side,int X,int b,int p,int i){
  return ((((size_t)side*5 + X)*Bn + b)*Pn + p)*Ln + i;
}

// ---------------- k_prep: lengths + weight tables (W2T [X][h][p], W2F frag-linear mp, W2B frag-linear all-X) ----------------
__global__ __launch_bounds__(256) void k_prep(
    const float* __restrict__ m1, const float* __restrict__ m2,
    const float* __restrict__ wff, const float* __restrict__ wfb,
    const float* __restrict__ wmp, const float* __restrict__ watt,
    const float* __restrict__ wmatt,
    float* __restrict__ W2T, float* __restrict__ W2F, float* __restrict__ W2B,
    int* __restrict__ lens){
  int t = threadIdx.x;
  const float* srcs[5] = {wff,wfb,wmp,watt,wmatt};
  if(blockIdx.x < 8){
    int b = blockIdx.x;
    __shared__ int cnt[2];
    if(t<2) cnt[t]=0;
    __syncthreads();
    if(t<Ln){
      if(m1[b*Ln+t]>0.5f) atomicAdd(&cnt[0],1);
      if(m2[b*Ln+t]>0.5f) atomicAdd(&cnt[1],1);
    }
    __syncthreads();
    if(t==0){
      lens[b]=cnt[0]; lens[8+b]=cnt[1];
      lens[16+b]=max(cnt[0]-1,0); lens[24+b]=max(cnt[1]-1,0);
    }
  } else if(blockIdx.x < 248){
    int idx = (blockIdx.x-8)*256 + t;     // < 5*768*16 = 61440
    int X = idx/(Pn*Hn);
    int r = idx%(Pn*Hn);
    int h = r/Pn, p = r%Pn;
    float w = srcs[X][p*Hn+h];
    W2T[idx] = w*w;                        // layout [X][h][p]
  } else if(blockIdx.x < 296){
    // W2F: fragment-linear fp32 w2 for mp: [ksg 24][half 2][64 lanes][4]
    int idx = (blockIdx.x-248)*256 + t;    // < 12288
    int ksg = idx>>9;
    int r   = idx&511;
    int half= r>>8;
    int li  = (r>>2)&63;
    int e4  = r&3;
    int h = ksg*32 + half*16 + ((li>>4)<<2) + e4;
    int p = li&15;
    float w = wmp[p*Hn+h];
    W2F[idx] = w*w;
  } else {
    // W2B: k_fin Phase-B frag-linear: [X 5][hh4 48][lane 64][4]
    // entry = w2[p = lane&15][h = (lane>>4)*192 + hh4*4 + e]
    int idx = (blockIdx.x-296)*256 + t;    // < 61440
    int X   = idx/12288;
    int r   = idx%12288;
    int hh4 = r>>8;
    int li  = (r>>2)&63;
    int e   = r&3;
    int h = (li>>4)*192 + hh4*4 + e;
    int p = li&15;
    float w = srcs[X][p*Hn+h];
    W2B[idx] = w*w;
  }
}

// ---------------- k_rows: 4 rows/block; masked rows + norms + bf16 split + p-in-thread weighted norms ----------------
// grid (Ln/4, Bn, 2), 256 thr.
__global__ __launch_bounds__(256) void k_rows(
    const float* __restrict__ ctx1, const float* __restrict__ m1,
    const float* __restrict__ ctx2, const float* __restrict__ m2,
    const float* __restrict__ W2T,
    float* __restrict__ c1f, float* __restrict__ c2f,
    unsigned short* __restrict__ c2h, unsigned short* __restrict__ c2l,
    float* __restrict__ n1, float* __restrict__ n2, float* __restrict__ wn){
  const int i0 = blockIdx.x*4, b = blockIdx.y, side = blockIdx.z;
  const float* ctx = side? ctx2 : ctx1;
  const float* msk = side? m2 : m1;
  float* dst = side? c2f : c1f;
  float* nD  = side? n2 : n1;
  const int t = threadIdx.x, w = t>>6, l = t&63;

  __shared__ float red4[4][4];
  __shared__ float redX[4][4][16];   // [wave][pq][r*4+pi]
  __shared__ float mkS[4];

  if(t<4) mkS[t] = msk[b*Ln+i0+t];

  // ---- Phase 1: masked write-out + bf16 split + norms (4 rows) ----
#pragma unroll
  for(int r=0;r<4;r++){
    const int i = i0+r;
    const float mk = msk[b*Ln+i];
    const size_t base = ((size_t)(b*Ln+i))*Hn;
    float ss = 0.f;
#pragma unroll
    for(int k=0;k<3;k++){
      float x = ctx[base + t + 256*k]*mk;
      dst[base + t + 256*k] = x;
      ss = fmaf(x,x,ss);
      if(side==1){
        int h = t+256*k;
        int kc = h>>6, hw = h&63, u = hw>>2, e = hw&3;
        int pos = ((u ^ (i&15))<<2) + e;
        size_t o = ((size_t)(b*12+kc)*128 + i)*64 + pos;
        unsigned hb = __float_as_uint(x) & 0xffff0000u;
        float rem = x - __uint_as_float(hb);
        c2h[o] = (unsigned short)(hb>>16);
        c2l[o] = (unsigned short)(__float_as_uint(rem)>>16);
      }
    }
    ss = wred_sum(ss);
    if(l==0) red4[r][w]=ss;
  }
  __syncthreads();
  if(t<4) nD[b*Ln+i0+t] = sqrtf(fmaxf(red4[t][0]+red4[t][1]+red4[t][2]+red4[t][3],0.f));

  // ---- Phase 2: weighted norms, thread = (hc: h-block of 12, pq: 4 p's) ----
  const int pq = t&3, hc = t>>2;
  const int h0 = hc*12;
  float v2r[4][12];
#pragma unroll
  for(int r=0;r<4;r++){
    const float mk = mkS[r];
    const float* src = ctx + ((size_t)(b*Ln+i0+r))*Hn + h0;
#pragma unroll
    for(int q=0;q<3;q++){
      float4 xv = *(const float4*)(src + q*4);
      v2r[r][q*4+0]=xv.x*xv.x*mk; v2r[r][q*4+1]=xv.y*xv.y*mk;
      v2r[r][q*4+2]=xv.z*xv.z*mk; v2r[r][q*4+3]=xv.w*xv.w*mk;
    }
  }
  for(int X=0;X<5;++X){
    float acc[4][4];
#pragma unroll
    for(int r=0;r<4;r++){ acc[r][0]=0.f; acc[r][1]=0.f; acc[r][2]=0.f; acc[r][3]=0.f; }
    const float* wb = W2T + (size_t)X*Hn*Pn + pq*4;
#pragma unroll
    for(int h=0;h<12;h++){
      float4 w4 = *(const float4*)(wb + (size_t)(h0+h)*Pn);
#pragma unroll
      for(int r=0;r<4;r++){
        acc[r][0]=fmaf(w4.x,v2r[r][h],acc[r][0]);
        acc[r][1]=fmaf(w4.y,v2r[r][h],acc[r][1]);
        acc[r][2]=fmaf(w4.z,v2r[r][h],acc[r][2]);
        acc[r][3]=fmaf(w4.w,v2r[r][h],acc[r][3]);
      }
    }
#pragma unroll
    for(int r=0;r<4;r++)
#pragma unroll
      for(int pi=0;pi<4;pi++){
        float v = acc[r][pi];
        v += __shfl_xor(v,4); v += __shfl_xor(v,8);
        v += __shfl_xor(v,16); v += __shfl_xor(v,32);
        acc[r][pi]=v;
      }
    if(l<4){
#pragma unroll
      for(int r=0;r<4;r++)
#pragma unroll
        for(int pi=0;pi<4;pi++) redX[w][l][r*4+pi]=acc[r][pi];
    }
    __syncthreads();
    if(t<64){
      int r = t>>4, p = t&15;
      int pqi = p>>2, pii = p&3;
      float s = redX[0][pqi][r*4+pii]+redX[1][pqi][r*4+pii]
               +redX[2][pqi][r*4+pii]+redX[3][pqi][r*4+pii];
      wn[wnIdx(side,X,b,p,i0+r)] = s;
    }
    __syncthreads();
  }
}

// ---------------- k_mm: MFMA split-bf16 e-tensor + cos ----------------
// grid (Bn, 32): block = (b, 4 i, all 128 j). 512 thr = 8 waves (jtp:4, ihalf:2).
__global__ __launch_bounds__(512) void k_mm(
    const float* __restrict__ c1f,
    const unsigned short* __restrict__ c2h, const unsigned short* __restrict__ c2l,
    const float* __restrict__ W2F, const float* __restrict__ WN,
    const float* __restrict__ n1, const float* __restrict__ n2,
    const float* __restrict__ m1, const float* __restrict__ m2,
    const int* __restrict__ lens,
    float* __restrict__ cosM,
    float* __restrict__ mvmax, float* __restrict__ mvmean,
    float* __restrict__ part){
  const int b = blockIdx.x, ig = blockIdx.y, ibase = ig*4;
  const int t = threadIdx.x, l = t&63;
  const int wid = __builtin_amdgcn_readfirstlane(t>>6);
  const int jtp = wid&3, ihalf = wid>>2;
  const int p = l&15, g4 = l>>4;

  __shared__ __align__(16) unsigned short sB2h[2][128][64];  // 32 KB
  __shared__ __align__(16) unsigned short sB2l[2][128][64];  // 32 KB
  __shared__ __align__(16) float sw2[2][1024];               // 8 KB [ks][half][64][4]
  __shared__ __align__(16) float sa[2][4][64];               // 2 KB (swizzled units)
  __shared__ float sm2s[Ln];
  __shared__ float red0[2][4][2][16][2];                     // [ihalf][jtp][ii][p][M,S]

  const size_t c2elem = (size_t)b*12*8192;   // ushort elements to chunk 0 of b

  // ---- prologue: DMA chunk 0 (B2 hi/lo, w2f), stage sm2 + a(kc0) ----
  {
#pragma unroll
    for(int k=0;k<2;k++){
      GLD_LDS((const char*)c2h + c2elem*2 + (2*wid+k)*1024 + l*16,
              (char*)&sB2h[0][0][0] + (2*wid+k)*1024);
      GLD_LDS((const char*)c2l + c2elem*2 + (2*wid+k)*1024 + l*16,
              (char*)&sB2l[0][0][0] + (2*wid+k)*1024);
    }
    if(wid>=4){
      int q = wid-4;
      GLD_LDS((const char*)W2F + q*1024 + l*16,
              (char*)&sw2[0][0] + q*1024);
    }
    if(t<Ln) sm2s[t] = m2[b*Ln+t];
    if(t<64){
      int row = t>>4, u = t&15;
      float4 av = *(const float4*)(c1f + ((size_t)(b*Ln+ibase+row))*Hn + u*4);
      *(float4*)&sa[0][row][(u ^ (row&3))<<2] = av;
    }
  }
  __syncthreads();

  f32x4 accE[2][2]; f32x4 accC[2];
#pragma unroll
  for(int q=0;q<2;q++){
    accC[q] = (f32x4){0.f,0.f,0.f,0.f};
#pragma unroll
    for(int ii=0;ii<2;ii++) accE[q][ii] = (f32x4){0.f,0.f,0.f,0.f};
  }

  for(int c=0; c<12; ++c){
    const int cur = c&1, nxt = cur^1;
    const bool more = (c+1<12);
    float4 aN;
    if(more){
      const size_t cb2 = (c2elem + (size_t)(c+1)*8192)*2;   // bytes
#pragma unroll
      for(int k=0;k<2;k++){
        GLD_LDS((const char*)c2h + cb2 + (2*wid+k)*1024 + l*16,
                (char*)&sB2h[nxt][0][0] + (2*wid+k)*1024);
        GLD_LDS((const char*)c2l + cb2 + (2*wid+k)*1024 + l*16,
                (char*)&sB2l[nxt][0][0] + (2*wid+k)*1024);
      }
      if(wid>=4){
        int q = wid-4;
        GLD_LDS((const char*)W2F + (c+1)*4096 + q*1024 + l*16,
                (char*)&sw2[nxt][0] + q*1024);
      }
      if(t<64){
        int row = t>>4, u = t&15;
        aN = *(const float4*)(c1f + ((size_t)(b*Ln+ibase+row))*Hn + (c+1)*64 + u*4);
      }
    }
#pragma unroll
    for(int ks=0; ks<2; ++ks){
      f32x4 w20 = *(const f32x4*)&sw2[cur][(ks*2+0)*256 + (l<<2)];
      f32x4 w21 = *(const f32x4*)&sw2[cur][(ks*2+1)*256 + (l<<2)];
      FragU Bh[2], Bl[2];
#pragma unroll
      for(int q=0;q<2;q++){
        int jt = jtp + 4*q;
        int j  = jt*16 + p;
        const char* bh = (const char*)&sB2h[cur][0][0] + j*128;
        const char* bl = (const char*)&sB2l[cur][0][0] + j*128;
        int u1 = (ks*8 + g4)     ^ (j&15);
        int u2 = (ks*8 + 4 + g4) ^ (j&15);
        uint2 h0 = *(const uint2*)(bh + (u1<<3));
        uint2 h1 = *(const uint2*)(bh + (u2<<3));
        uint2 l0 = *(const uint2*)(bl + (u1<<3));
        uint2 l1 = *(const uint2*)(bl + (u2<<3));
        Bh[q].u[0]=h0.x; Bh[q].u[1]=h0.y; Bh[q].u[2]=h1.x; Bh[q].u[3]=h1.y;
        Bl[q].u[0]=l0.x; Bl[q].u[1]=l0.y; Bl[q].u[2]=l1.x; Bl[q].u[3]=l1.y;
      }
      if(ihalf==0){
        int ar = p&3;
        const float* sar = &sa[cur][ar][0];
        f32x4 a0 = *(const f32x4*)(sar + (((ks*8+g4)  ^ar)<<2));
        f32x4 a1 = *(const f32x4*)(sar + (((ks*8+4+g4)^ar)<<2));
        float xv[8] = {a0[0],a0[1],a0[2],a0[3], a1[0],a1[1],a1[2],a1[3]};
        FragU Ah, Al; split8(xv, Ah, Al);
#pragma unroll
        for(int q=0;q<2;q++){
          accC[q] = MFMA16(Bh[q].v, Ah.v, accC[q]);
          accC[q] = MFMA16(Bh[q].v, Al.v, accC[q]);
          accC[q] = MFMA16(Bl[q].v, Ah.v, accC[q]);
        }
      }
#pragma unroll
      for(int ii=0;ii<2;ii++){
        int row = ihalf*2+ii;
        const float* sar = &sa[cur][row][0];
        f32x4 a0 = *(const f32x4*)(sar + (((ks*8+g4)  ^(row&3))<<2));
        f32x4 a1 = *(const f32x4*)(sar + (((ks*8+4+g4)^(row&3))<<2));
        float xv[8] = {a0[0]*w20[0], a0[1]*w20[1], a0[2]*w20[2], a0[3]*w20[3],
                       a1[0]*w21[0], a1[1]*w21[1], a1[2]*w21[2], a1[3]*w21[3]};
        FragU Ah, Al; split8(xv, Ah, Al);
#pragma unroll
        for(int q=0;q<2;q++){
          accE[q][ii] = MFMA16(Bh[q].v, Ah.v, accE[q][ii]);
          accE[q][ii] = MFMA16(Bh[q].v, Al.v, accE[q][ii]);
          accE[q][ii] = MFMA16(Bl[q].v, Ah.v, accE[q][ii]);
        }
      }
    }
    if(more && t<64){
      int row = t>>4, u = t&15;
      *(float4*)&sa[nxt][row][(u ^ (row&3))<<2] = aN;
    }
    __syncthreads();   // one barrier/chunk: readers done + next DMA drained
  }

  // ---- epilogue: normalize, side0 (final), side1 (partial->part), cos ----
  const int len2 = min(max(lens[8+b],1),Ln);
  float sq1[2][4];
#pragma unroll
  for(int q=0;q<2;q++){
    int jt = jtp+4*q;
#pragma unroll
    for(int r=0;r<4;r++){
      int j = jt*16 + g4*4 + r;
      sq1[q][r] = sqrtf(fmaxf(WN[wnIdx(1,2,b,p,j)],0.f));
    }
  }
  float s1M[2][4], s1S[2][4];
#pragma unroll
  for(int q=0;q<2;q++)
#pragma unroll
    for(int r=0;r<4;r++){ s1M[q][r]=NINF; s1S[q][r]=0.f; }

#pragma unroll
  for(int ii=0;ii<2;ii++){
    int iR = ibase + ihalf*2 + ii;
    float sr = sqrtf(fmaxf(WN[wnIdx(0,2,b,p,iR)],0.f));
    float mr = m1[b*Ln+iR];
    float vmax=NINF, vsum=0.f;
#pragma unroll
    for(int q=0;q<2;q++){
      int jt = jtp+4*q;
#pragma unroll
      for(int r=0;r<4;r++){
        int j = jt*16 + g4*4 + r;
        float ev = accE[q][ii][r] / fmaxf(sr*sq1[q][r], EPSF);
        if(sm2s[j]!=0.f){ vmax=fmaxf(vmax,ev); vsum+=ev; }
        if(mr!=0.f){ s1M[q][r]=fmaxf(s1M[q][r],ev); s1S[q][r]+=ev; }
      }
    }
    vmax = fmaxf(vmax, __shfl_xor(vmax,16)); vmax = fmaxf(vmax, __shfl_xor(vmax,32));
    vsum += __shfl_xor(vsum,16); vsum += __shfl_xor(vsum,32);
    if(l<16){ red0[ihalf][jtp][ii][l][0]=vmax; red0[ihalf][jtp][ii][l][1]=vsum; }
  }
  float* red1 = (float*)&sB2h[0][0][0];   // alias (sB2 dead), 16 KB
  if(ihalf==1){
#pragma unroll
    for(int q=0;q<2;q++)
#pragma unroll
      for(int r=0;r<4;r++){
        int idx = (((jtp*2+q)*64 + l)*4 + r)*2;
        red1[idx]   = s1M[q][r];
        red1[idx+1] = s1S[q][r];
      }
  }
  __syncthreads();
  if(t<64){
    int ih_=t>>5, ii_=(t>>4)&1, p_=t&15;
    float M=NINF,S=0.f;
#pragma unroll
    for(int jq=0;jq<4;jq++){ M=fmaxf(M,red0[ih_][jq][ii_][p_][0]); S+=red0[ih_][jq][ii_][p_][1]; }
    int iR = ibase + ih_*2 + ii_;
    size_t o = ((size_t)(b*Ln+iR))*Pn + p_;
    mvmax[o]=M; mvmean[o]=S/(float)len2;   // side0: final (all j in block)
  }
  if(ihalf==0){
#pragma unroll
    for(int q=0;q<2;q++){
      int jt = jtp+4*q;
#pragma unroll
      for(int r=0;r<4;r++){
        int j = jt*16 + g4*4 + r;
        int idx = (((jtp*2+q)*64 + l)*4 + r)*2;
        float M = fmaxf(s1M[q][r], red1[idx]);
        float S = s1S[q][r] + red1[idx+1];
        size_t o = ((((size_t)(b*Ln+j))*Pn + p)*32 + ig)*2;
        part[o]=M; part[o+1]=S;
        float nj = fmaxf(n2[b*Ln+j], EPSF);
        if(p<4){
          int iR = ibase + p;
          float ni = fmaxf(n1[b*Ln+iR], EPSF);
          cosM[((size_t)(b*Ln+iR))*Ln + j] = accC[q][r]/(ni*nj);
        }
      }
    }
  }
}

// ---------------- k_mm2: combine side1 partials over 32 i-tiles ----------------
__global__ __launch_bounds__(256) void k_mm2(
    const float* __restrict__ part, const int* __restrict__ lens,
    float* __restrict__ mvmax, float* __restrict__ mvmean){
  int g = blockIdx.x*256 + threadIdx.x;   // 16384 = B*L*P
  int b = g>>11;
  const float4* q = (const float4*)(part + (size_t)g*64);
  float mx = NINF, sm = 0.f;
#pragma unroll
  for(int k=0;k<16;k++){
    float4 v = q[k];
    mx = fmaxf(mx, fmaxf(v.x, v.z));
    sm += v.y + v.w;
  }
  int len1 = min(max(lens[b],1),Ln);
  size_t o = (size_t)Bn*Ln*Pn + g;        // side 1 block of mv arrays
  mvmax[o] = mx;
  mvmean[o] = sm/(float)len1;
}

// ---------------- k_fin: attention + all 102 features; 4 rows/block (R12 best config) ----------------
// grid (16, Ln/4): x = side*8+b → XCD = b
// R11-R15 record: five k_fin geometries landed 44.2-52µs; this exact config (R12)
// is the measured minimum (44.2µs). The floor is the dependent L2 load chain in
// the attention loop — reuse/occupancy/wave-split/fusion all regressed. Only
// change vs R12: attention loop unroll 2→4 (VGPR headroom exists; grid-capped).
#define HPAD 784              // 768 + 4*4
__global__ __launch_bounds__(256) void k_fin(
    const float* __restrict__ c1f, const float* __restrict__ c2f,
    const float* __restrict__ cosM,
    const float* __restrict__ n1, const float* __restrict__ n2,
    const float* __restrict__ wn, const float* __restrict__ W2B,
    const float* __restrict__ mvmax, const float* __restrict__ mvmean,
    const int* __restrict__ lens,
    const float* __restrict__ m1, const float* __restrict__ m2,
    float* __restrict__ out){
  const int x = blockIdx.x, side = x>>3, b = x&7;
  const int r0 = blockIdx.y*4;
  const int t = threadIdx.x, w = t>>6, l = t&63;
  const float* selfF  = side? c2f : c1f;
  const float* otherF = side? c1f : c2f;
  const float* nSelf  = side? n2 : n1;
  const float* nOther = side? n1 : n2;
  const float* mInner = side? m1 : m2;
  const float* mSelfm = side? m2 : m1;
  int lenI = side? lens[b]    : lens[8+b];
  int lpO  = side? lens[16+b] : lens[24+b];
  lenI = min(max(lenI,1),Ln);
  lpO  = min(max(lpO,0),Ln-1);

  __shared__ float cS[4*Ln];
  __shared__ float mS[Ln];
  __shared__ __align__(16) float sV1[4][HPAD];
  __shared__ __align__(16) float sF[HPAD], sB[HPAD];
  __shared__ __align__(16) float sAS[4][HPAD], sAM[4][HPAD];
  __shared__ float redm[4][4], reds[4][4];

  // ---- stage (padded: float4-unit q -> q + q/48; scalar h -> h + 4*(h/192)) ----
  {
    if(side==0){
      const float* crow = cosM + ((size_t)(b*Ln+r0))*Ln;
      for(int idx=t; idx<4*Ln; idx+=256) cS[idx]=crow[idx];
    } else {
      for(int idx=t; idx<4*Ln; idx+=256){
        int jj = idx&127, rp = idx>>7;   // transposed: cos^T[r][j] = cosM[j][r]
        cS[rp*Ln+jj] = cosM[((size_t)(b*Ln+jj))*Ln + r0+rp];
      }
    }
    if(t<Ln) mS[t]=mInner[b*Ln+t];
    const float4* s4 = (const float4*)(selfF + ((size_t)(b*Ln+r0))*Hn);
    for(int idx=t; idx<4*Hn/4; idx+=256){
      int row = idx/192, q = idx - row*192;
      ((float4*)&sV1[row][0])[q + q/48] = s4[idx];
    }
    const float4* f4 = (const float4*)(otherF + ((size_t)(b*Ln+lpO))*Hn);
    const float4* b4 = (const float4*)(otherF + ((size_t)(b*Ln))*Hn);
    if(t<Hn/4){
      ((float4*)sF)[t + t/48]=f4[t];
      ((float4*)sB)[t + t/48]=b4[t];
    }
  }
  __syncthreads();

  // ---- attention accumulation (4 rows, h = 3t..3t+2); jj < lenI only ----
  float aS[4][3], aM[4][3];
#pragma unroll
  for(int r=0;r<4;r++)
#pragma unroll
    for(int k=0;k<3;k++){ aS[r][k]=0.f; aM[r][k]=NINF; }
  {
    const float* src = otherF + (size_t)b*Ln*Hn;
#pragma unroll 4
    for(int jj=0; jj<lenI; ++jj){        // jj<lenI => mS[jj]!=0 (prefix mask)
      float3 vk = ((const float3*)(src + (size_t)jj*Hn))[t];
      float c0=cS[jj], c1v=cS[Ln+jj], c2v=cS[2*Ln+jj], c3v=cS[3*Ln+jj];
      aS[0][0]=fmaf(vk.x,c0 ,aS[0][0]); aS[0][1]=fmaf(vk.y,c0 ,aS[0][1]); aS[0][2]=fmaf(vk.z,c0 ,aS[0][2]);
      aS[1][0]=fmaf(vk.x,c1v,aS[1][0]); aS[1][1]=fmaf(vk.y,c1v,aS[1][1]); aS[1][2]=fmaf(vk.z,c1v,aS[1][2]);
      aS[2][0]=fmaf(vk.x,c2v,aS[2][0]); aS[2][1]=fmaf(vk.y,c2v,aS[2][1]); aS[2][2]=fmaf(vk.z,c2v,aS[2][2]);
      aS[3][0]=fmaf(vk.x,c3v,aS[3][0]); aS[3][1]=fmaf(vk.y,c3v,aS[3][1]); aS[3][2]=fmaf(vk.z,c3v,aS[3][2]);
      aM[0][0]=fmaxf(aM[0][0],vk.x*c0 ); aM[0][1]=fmaxf(aM[0][1],vk.y*c0 ); aM[0][2]=fmaxf(aM[0][2],vk.z*c0 );
      aM[1][0]=fmaxf(aM[1][0],vk.x*c1v); aM[1][1]=fmaxf(aM[1][1],vk.y*c1v); aM[1][2]=fmaxf(aM[1][2],vk.z*c1v);
      aM[2][0]=fmaxf(aM[2][0],vk.x*c2v); aM[2][1]=fmaxf(aM[2][1],vk.y*c2v); aM[2][2]=fmaxf(aM[2][2],vk.z*c2v);
      aM[3][0]=fmaxf(aM[3][0],vk.x*c3v); aM[3][1]=fmaxf(aM[3][1],vk.y*c3v); aM[3][2]=fmaxf(aM[3][2],vk.z*c3v);
    }
  }

  // ---- softmax over h (4 rows) ----
  {
#pragma unroll
    for(int r=0;r<4;r++){
      float lm = fmaxf(fmaxf(aS[r][0],aS[r][1]),aS[r][2]);
      lm = wred_max(lm);
      if(l==0) redm[r][w]=lm;
    }
  }
  __syncthreads();
  float bm[4];
#pragma unroll
  for(int r=0;r<4;r++)
    bm[r] = fmaxf(fmaxf(redm[r][0],redm[r][1]),fmaxf(redm[r][2],redm[r][3]));
  float ev[4][3];
  {
#pragma unroll
    for(int r=0;r<4;r++){
      float es=0.f;
#pragma unroll
      for(int k=0;k<3;k++){ ev[r][k]=expf(aS[r][k]-bm[r]); es+=ev[r][k]; }
      es = wred_sum(es);
      if(l==0) reds[r][w]=es;
    }
  }
  __syncthreads();
  {
    const float u = 1.f/(float)Hn;
#pragma unroll
    for(int r=0;r<4;r++){
      float smr = mSelfm[b*Ln+r0+r];
      float bs = reds[r][0]+reds[r][1]+reds[r][2]+reds[r][3];
      float inv = 1.f/fmaxf(bs,EPSF);
#pragma unroll
      for(int k=0;k<3;k++){
        int h = 3*t+k;
        int hi = h + ((h/192)<<2);
        sAS[r][hi] = (smr!=0.f)? ev[r][k]*inv : u;
        sAM[r][hi] = aM[r][k];
      }
    }
  }
  __syncthreads();

  // ---- Phase A (all 4 waves, row = w) + Phase C (t<128) ----
  {
    int rr = w;
    float cmx=NINF, csm=0.f;
    float ca = cS[rr*Ln + l], cb = cS[rr*Ln + l + 64];
    if(mS[l]!=0.f){ cmx=ca; csm=ca; }
    if(mS[l+64]!=0.f){ cmx=fmaxf(cmx,cb); csm+=cb; }
    cmx = wred_max(cmx); csm = wred_sum(csm);
    if(l==0){
      float* op = out + ((size_t)((b*2+side)*Ln + r0+rr))*Dn;
      op[0] = cmx;
      op[1] = csm/(float)lenI;
    }
  }
  if(t<128){
    int rr = t>>5, qq = t&31, p = qq&15;
    size_t o = ((size_t)((side*Bn+b)*Ln + r0+rr))*Pn + p;
    float* op = out + ((size_t)((b*2+side)*Ln + r0+rr))*Dn;
    if(qq<16) op[36+p] = mvmax[o];
    else      op[52+p] = mvmean[o];
  }

  // ---- Phase B: wave w handles mi=w for 4 rows; lane = (p, hq) ----
  {
    const int Xids[4] = {0,1,3,4};
    const int offS[4] = {2,19,68,85};
    const int X = Xids[w], offs = offS[w];
    const bool dyn = (w>=2);
    const int p = l&15, hq = l>>4;
    const int hb = hq*196;                  // padded per-group base
    const float4* wB = (const float4*)W2B + (size_t)X*3072 + l;  // [h4*64]
    float acc[4]={0,0,0,0}, s0[4]={0,0,0,0};
    float sna[4]={0,0,0,0}, sn[4]={0,0,0,0};
    if(!dyn){
      const float* bvp = (w==0)? sF : sB;
#pragma unroll 4
      for(int h4=0; h4<48; ++h4){
        float4 w4 = wB[h4*64];
        float4 bv = *(const float4*)(bvp + hb + h4*4);
#pragma unroll
        for(int r=0;r<4;r++){
          float4 v = *(const float4*)(&sV1[r][hb + h4*4]);
          float pr;
          pr=v.x*bv.x; acc[r]=fmaf(w4.x,pr,acc[r]); s0[r]+=pr;
          pr=v.y*bv.y; acc[r]=fmaf(w4.y,pr,acc[r]); s0[r]+=pr;
          pr=v.z*bv.z; acc[r]=fmaf(w4.z,pr,acc[r]); s0[r]+=pr;
          pr=v.w*bv.w; acc[r]=fmaf(w4.w,pr,acc[r]); s0[r]+=pr;
        }
      }
    } else {
      const float (*bvp)[HPAD] = (w==2)? sAS : sAM;
#pragma unroll 2
      for(int h4=0; h4<48; ++h4){
        float4 w4 = wB[h4*64];
#pragma unroll
        for(int r=0;r<4;r++){
          float4 bv = *(const float4*)(&bvp[r][hb + h4*4]);
          float4 v  = *(const float4*)(&sV1[r][hb + h4*4]);
          float pr, bb;
          pr=v.x*bv.x; bb=bv.x*bv.x;
          acc[r]=fmaf(w4.x,pr,acc[r]); sna[r]=fmaf(w4.x,bb,sna[r]); s0[r]+=pr; sn[r]+=bb;
          pr=v.y*bv.y; bb=bv.y*bv.y;
          acc[r]=fmaf(w4.y,pr,acc[r]); sna[r]=fmaf(w4.y,bb,sna[r]); s0[r]+=pr; sn[r]+=bb;
          pr=v.z*bv.z; bb=bv.z*bv.z;
          acc[r]=fmaf(w4.z,pr,acc[r]); sna[r]=fmaf(w4.z,bb,sna[r]); s0[r]+=pr; sn[r]+=bb;
          pr=v.w*bv.w; bb=bv.w*bv.w;
          acc[r]=fmaf(w4.w,pr,acc[r]); sna[r]=fmaf(w4.w,bb,sna[r]); s0[r]+=pr; sn[r]+=bb;
        }
      }
    }
#pragma unroll
    for(int r=0;r<4;r++){
      acc[r]=qred_sum(acc[r]); s0[r]=qred_sum(s0[r]);
      if(dyn){ sna[r]=qred_sum(sna[r]); sn[r]=qred_sum(sn[r]); }
    }
#pragma unroll
    for(int rr=0; rr<4; ++rr){
      const int r = r0+rr;
      float* op = out + ((size_t)((b*2+side)*Ln + r))*Dn;
      if(l<16){
        float wa = fmaxf(wn[wnIdx(side,X,b,l,r)],0.f);
        float wb = dyn? fmaxf(sna[rr],0.f)
                      : fmaxf(wn[wnIdx(1-side,X,b,l,(w==0? lpO:0))],0.f);
        float mul = acc[rr]/(fmaxf(sqrtf(wa),EPSF)*fmaxf(sqrtf(wb),EPSF));
        op[offs+1+l] = mul;
      }
      if(l==0){
        float nb = dyn? sqrtf(fmaxf(sn[rr],0.f)) : nOther[b*Ln + (w==0? lpO : 0)];
        float nv1 = nSelf[b*Ln+r];
        op[offs] = s0[rr]/(fmaxf(nv1,EPSF)*fmaxf(nb,EPSF));
      }
    }
  }
}

extern "C" void kernel_launch(void* const* d_in, const int* in_sizes, int n_in,
                              void* d_out, int out_size, void* d_ws, size_t ws_size,
                              hipStream_t stream) {
  const float* ctx1 = (const float*)d_in[0];
  const float* m1   = (const float*)d_in[1];
  const float* ctx2 = (const float*)d_in[2];
  const float* m2   = (const float*)d_in[3];
  const float* wff  = (const float*)d_in[4];
  const float* wfb  = (const float*)d_in[5];
  const float* wmp  = (const float*)d_in[6];
  const float* watt = (const float*)d_in[7];
  const float* wmatt= (const float*)d_in[8];
  float* out = (float*)d_out;
  float* W = (float*)d_ws;
  int* lens = (int*)(W + OFF_LENS);
  unsigned short* c2h = (unsigned short*)(W + OFF_C2H);
  unsigned short* c2l = (unsigned short*)(W + OFF_C2L);

  k_prep<<<dim3(8 + 240 + 48 + 240), 256, 0, stream>>>(m1,m2,wff,wfb,wmp,watt,wmatt,
      W+OFF_W2T, W+OFF_W2F, W+OFF_W2B, lens);
  k_rows<<<dim3(Ln/4,Bn,2), 256, 0, stream>>>(ctx1,m1,ctx2,m2, W+OFF_W2T,
      W+OFF_C1F, W+OFF_C2F, c2h, c2l, W+OFF_N1, W+OFF_N2, W+OFF_WN);
  k_mm<<<dim3(Bn, 32), 512, 0, stream>>>(W+OFF_C1F, c2h, c2l,
      W+OFF_W2F, W+OFF_WN, W+OFF_N1, W+OFF_N2, m1, m2, lens,
      W+OFF_COS, W+OFF_MVMAX, W+OFF_MVMEAN, W+OFF_PART);
  k_mm2<<<dim3((Bn*Ln*Pn)/256), 256, 0, stream>>>(W+OFF_PART, lens,
      W+OFF_MVMAX, W+OFF_MVMEAN);
  k_fin<<<dim3(16, Ln/4), 256, 0, stream>>>(W+OFF_C1F, W+OFF_C2F, W+OFF_COS,
      W+OFF_N1, W+OFF_N2, W+OFF_WN, W+OFF_W2B, W+OFF_MVMAX, W+OFF_MVMEAN,
      lens, m1, m2, out);
}